// Round 8
// baseline (304.891 us; speedup 1.0000x reference)
//
#include <hip/hip_runtime.h>
#include <hip/hip_bf16.h>

#define B_   32
#define C_   128
#define H_   56
#define W_   56
#define HW_  (H_*W_)
#define BHW_ (B_*HW_)        // 100352 = 784*128; 3136 = 49*64
#define K5_  5
#define KK_  25
#define CR_  32
#define CE_  512
#define EPS_ 1e-6f

typedef __hip_bfloat16 bf16;
typedef __attribute__((ext_vector_type(8))) short short8;   // 8 bf16 (4 VGPRs)
typedef __attribute__((ext_vector_type(4))) float f32x4;

// ---------- workspace layout (bytes) ----------
// pooled fp32 [B*C]        @ 0         (16,384)
// dyn    fp32 [B*C*25]     @ 16,384    (409,600)
// gx2    fp32 [B*CE]       @ 425,984   (65,536)
// scale  fp32 [B*CE]       @ 491,520   (65,536)
// sb     fp32 [C]          @ 557,056   (512)
// weB    bf16 [CE*C]       @ 557,568   (131,072)
// wsB    bf16 [C*CE]       @ 688,640   (131,072)
// yT     bf16 [BHW][C]     @ 819,712   (25,690,112)
// z      bf16 [B][C][HW]   @ 26,509,824 (25,690,112)
// (eT / sws eliminated: expand recomputed in fused_shrink)

__device__ __forceinline__ float wave_reduce_sum(float v) {
#pragma unroll
  for (int off = 32; off > 0; off >>= 1) v += __shfl_down(v, off, 64);
  return v;
}
__device__ __forceinline__ float bf2f(unsigned short u) {
  return __uint_as_float(((unsigned)u) << 16);
}
__device__ __forceinline__ unsigned short f2bf_bits(float f) {
  bf16 h = __float2bfloat16(f);
  unsigned short u;
  __builtin_memcpy(&u, &h, 2);
  return u;
}
// sigmoid-form GELU: v * sigmoid(1.702 v)
__device__ __forceinline__ float fast_gelu(float v) {
  float t = __expf(-1.702f * v);
  return v * __builtin_amdgcn_rcpf(1.0f + t);
}
// async global->LDS, 16B per lane; LDS dest = wave-uniform base + lane*16
__device__ __forceinline__ void glds16(const void* g, void* l) {
  __builtin_amdgcn_global_load_lds(
      (const __attribute__((address_space(1))) unsigned int*)g,
      (__attribute__((address_space(3))) unsigned int*)l, 16, 0, 0);
}

// ---------------- K0: merged prep (weights->bf16, gx2=0, sb, pool) ----------------
// blocks 0..575: convert/zero; 576..703: sb[c]; 704..4799: pool (bc = bx-704)
__global__ __launch_bounds__(256) void prep_all(const float* __restrict__ we,
                                                const float* __restrict__ ws,
                                                const float* __restrict__ beta,
                                                const float* __restrict__ x,
                                                bf16* __restrict__ weB,
                                                bf16* __restrict__ wsB,
                                                float* __restrict__ gx2,
                                                float* __restrict__ sb,
                                                float* __restrict__ pooled) {
  int bx = blockIdx.x;
  if (bx < 576) {
    int i = bx * 256 + threadIdx.x;
    if (i < CE_ * C_)          weB[i] = __float2bfloat16(we[i]);
    else if (i < 2 * CE_ * C_) wsB[i - CE_ * C_] = __float2bfloat16(ws[i - CE_ * C_]);
    else                       gx2[i - 2 * CE_ * C_] = 0.f;
  } else if (bx < 704) {
    int c = bx - 576;
    const float* wp = ws + (size_t)c * CE_;
    float acc = 0.f;
    for (int o = threadIdx.x; o < CE_; o += 256) acc += wp[o] * beta[o];
    acc = wave_reduce_sum(acc);
    __shared__ float red[4];
    int lane = threadIdx.x & 63, wid = threadIdx.x >> 6;
    if (lane == 0) red[wid] = acc;
    __syncthreads();
    if (threadIdx.x == 0) sb[c] = red[0] + red[1] + red[2] + red[3];
  } else {
    int bc = bx - 704;
    const float4* xp4 = reinterpret_cast<const float4*>(x + (size_t)bc * HW_);
    float s = 0.f;
    for (int i = threadIdx.x; i < 784; i += 256) {
      float4 v = xp4[i];
      s += (v.x + v.y) + (v.z + v.w);
    }
    s = wave_reduce_sum(s);
    __shared__ float redp[4];
    int lane = threadIdx.x & 63, wid = threadIdx.x >> 6;
    if (lane == 0) redp[wid] = s;
    __syncthreads();
    if (threadIdx.x == 0) pooled[bc] = (redp[0] + redp[1] + redp[2] + redp[3]) * (1.0f / HW_);
  }
}

// ---------------- K2: fc1 -> LN1 -> fc2 (dyn weights) ----------------
__global__ __launch_bounds__(256) void fc_kernel(const float* __restrict__ pooled,
                                                 const float* __restrict__ w_fc1,
                                                 const float* __restrict__ ln1_w,
                                                 const float* __restrict__ ln1_b,
                                                 const float* __restrict__ w_fc2,
                                                 float* __restrict__ dyn) {
  int b = blockIdx.x;
  int tid = threadIdx.x;
  __shared__ float sp[C_];
  __shared__ float sh[CR_];
  __shared__ float shn[CR_];
  __shared__ float stats[2];
  if (tid < C_) sp[tid] = pooled[b * C_ + tid];
  __syncthreads();
  if (tid < CR_) {
    float acc = 0.f;
    const float* wr = w_fc1 + tid * C_;
#pragma unroll 4
    for (int c = 0; c < C_; ++c) acc += sp[c] * wr[c];
    sh[tid] = acc;
  }
  __syncthreads();
  if (tid == 0) {
    float u = 0.f;
    for (int j = 0; j < CR_; ++j) u += sh[j];
    u *= (1.0f / CR_);
    float v = 0.f;
    for (int j = 0; j < CR_; ++j) { float d = sh[j] - u; v += d * d; }
    v *= (1.0f / CR_);
    stats[0] = u;
    stats[1] = rsqrtf(v + EPS_);
  }
  __syncthreads();
  if (tid < CR_) shn[tid] = (sh[tid] - stats[0]) * stats[1] * ln1_w[tid] + ln1_b[tid];
  __syncthreads();
  for (int i = tid; i < C_ * KK_; i += 256) {
    const float* wr = w_fc2 + i * CR_;
    float acc = 0.f;
#pragma unroll
    for (int j = 0; j < CR_; ++j) acc += shn[j] * wr[j];
    dyn[b * (C_ * KK_) + i] = acc;
  }
}

// ---------------- K3a: dynamic depthwise 5x5 conv -> z (bf16, [b][c][hw]) ----------------
__global__ __launch_bounds__(256) void conv_kernel(const float* __restrict__ x,
                                                   const float* __restrict__ dyn,
                                                   bf16* __restrict__ z) {
  int bc = blockIdx.x;
  int b = bc >> 7;
  int c = bc & 127;
  int tid = threadIdx.x;
  __shared__ float xs[(H_ + 4) * 64];   // rows -2..57 at (r+2)*64; 15,360 B
  __shared__ float wks[KK_];
  {  // zero halo rows 0,1,58,59 (full) — 4*64 = 256 = blockDim
    int r = tid >> 6;
    int rr = (r < 2) ? r : (56 + r);
    xs[rr * 64 + (tid & 63)] = 0.f;
  }
  if (tid < 224) {  // zero halo cols 0,1,58,59 of data rows 2..57
    int r = tid >> 2, q = tid & 3;
    int col = (q < 2) ? q : (56 + q);
    xs[(r + 2) * 64 + col] = 0.f;
  }
  if (tid < KK_) wks[tid] = dyn[b * (C_ * KK_) + c * KK_ + tid];
  const float4* xp4 = reinterpret_cast<const float4*>(x + (size_t)bc * HW_);
  for (int i = tid; i < 784; i += 256) {
    float4 v = xp4[i];
    int h = i / 14, w4 = (i % 14) * 4;
    float* dst = &xs[(h + 2) * 64 + 2 + w4];
    dst[0] = v.x; dst[1] = v.y; dst[2] = v.z; dst[3] = v.w;
  }
  __syncthreads();
  float wr[KK_];
#pragma unroll
  for (int j = 0; j < KK_; ++j) wr[j] = wks[j];
  for (int g = tid; g < 784; g += 256) {
    int h = g / 14;
    int w4 = (g % 14) * 4;
    float a0 = 0.f, a1 = 0.f, a2 = 0.f, a3 = 0.f;
#pragma unroll
    for (int dh = 0; dh < K5_; ++dh) {
      const float* row = &xs[(h + dh) * 64 + w4];   // padded row h+dh-2
      float4 va = *reinterpret_cast<const float4*>(row);
      float4 vb = *reinterpret_cast<const float4*>(row + 4);
      float v0 = va.x, v1 = va.y, v2 = va.z, v3 = va.w;
      float v4 = vb.x, v5 = vb.y, v6 = vb.z, v7 = vb.w;
      float u0 = wr[dh * 5 + 0], u1 = wr[dh * 5 + 1], u2 = wr[dh * 5 + 2];
      float u3 = wr[dh * 5 + 3], u4 = wr[dh * 5 + 4];
      a0 += v0 * u0 + v1 * u1 + v2 * u2 + v3 * u3 + v4 * u4;
      a1 += v1 * u0 + v2 * u1 + v3 * u2 + v4 * u3 + v5 * u4;
      a2 += v2 * u0 + v3 * u1 + v4 * u2 + v5 * u3 + v6 * u4;
      a3 += v3 * u0 + v4 * u1 + v5 * u2 + v6 * u3 + v7 * u4;
    }
    size_t base = (size_t)bc * HW_ + h * W_ + w4;
    ushort4 pk = make_ushort4(f2bf_bits(a0), f2bf_bits(a1), f2bf_bits(a2), f2bf_bits(a3));
    *reinterpret_cast<ushort4*>(reinterpret_cast<unsigned short*>(z) + base) = pk;
  }
}

// ---------------- K3b: channel LN over z -> yT (bf16, [j][c]); vectorized loads ----------------
__global__ __launch_bounds__(256) void ln_kernel(const bf16* __restrict__ z,
                                                 const float* __restrict__ ln2_w,
                                                 const float* __restrict__ ln2_b,
                                                 bf16* __restrict__ yT) {
  int hw0 = blockIdx.x * 64;
  int b = blockIdx.y;
  int tid = threadIdx.x;
  int wq = tid & 63;
  int cq = tid >> 6;
  __shared__ unsigned short zt[C_][64];     // 16 KB
  __shared__ unsigned short yt[64][136];    // 17.4 KB transpose buffer (rows 16B-aligned)
  __shared__ float redS[4][64];
  __shared__ float redQ[4][64];
  __shared__ float meanArr[64];
  __shared__ float invArr[64];
  const unsigned short* zp = reinterpret_cast<const unsigned short*>(z);
#pragma unroll
  for (int i = 0; i < 4; ++i) {
    int t = tid + 256 * i;
    int c = t >> 3, ch = t & 7;
    int4 v = *reinterpret_cast<const int4*>(zp + ((size_t)(b * C_ + c)) * HW_ + hw0 + ch * 8);
    *reinterpret_cast<int4*>(&zt[c][ch * 8]) = v;
  }
  __syncthreads();
  float s = 0.f, q = 0.f;
#pragma unroll 4
  for (int k = 0; k < 32; ++k) {
    float v = bf2f(zt[cq * 32 + k][wq]);
    s += v;
    q += v * v;
  }
  redS[cq][wq] = s;
  redQ[cq][wq] = q;
  __syncthreads();
  if (cq == 0) {
    float ss = redS[0][wq] + redS[1][wq] + redS[2][wq] + redS[3][wq];
    float qq = redQ[0][wq] + redQ[1][wq] + redQ[2][wq] + redQ[3][wq];
    float m = ss * (1.0f / C_);
    float var = qq * (1.0f / C_) - m * m;
    meanArr[wq] = m;
    invArr[wq] = rsqrtf(fmaxf(var, 0.f) + EPS_);
  }
  __syncthreads();
  float m = meanArr[wq], iv = invArr[wq];
#pragma unroll
  for (int g = 0; g < 4; ++g) {
    unsigned short pk[8];
#pragma unroll
    for (int i = 0; i < 8; ++i) {
      int c = cq * 32 + g * 8 + i;
      float v = bf2f(zt[c][wq]);
      pk[i] = f2bf_bits((v - m) * iv * ln2_w[c] + ln2_b[c]);
    }
    int4 t;
    __builtin_memcpy(&t, pk, 16);
    *reinterpret_cast<int4*>(&yt[wq][cq * 32 + g * 8]) = t;
  }
  __syncthreads();
  unsigned short* yp = reinterpret_cast<unsigned short*>(yT);
#pragma unroll
  for (int i = 0; i < 4; ++i) {
    int t = tid + 256 * i;
    int row = t >> 4, ch = t & 15;
    int4 v = *reinterpret_cast<const int4*>(&yt[row][ch * 8]);
    *reinterpret_cast<int4*>(yp + ((size_t)(b * HW_ + hw0 + row)) * C_ + ch * 8) = v;
  }
}

// ---------------- K4: gx2 pass (unchanged; ~34 µs measured) ----------------
__global__ __launch_bounds__(256, 4) void gx2_pass(const bf16* __restrict__ yT,
                                                   const bf16* __restrict__ weB,
                                                   float* __restrict__ gx2) {
  int j0 = blockIdx.x * 128;
  int o0 = blockIdx.y * 128;
  int tid = threadIdx.x;
  int lane = tid & 63, wid = tid >> 6;
  int wm = wid >> 1, wn = wid & 1;
  int quad = lane >> 4, l15 = lane & 15;
  __shared__ __align__(16) char smem[32768];   // dbuf: buf t @ (t&1)*16384 {A 8K, B 8K}
  const short* yS = reinterpret_cast<const short*>(yT);
  const short* weS = reinterpret_cast<const short*>(weB);
  int sr = (wid * 2) * 16 + (lane >> 2);
  int scp = lane & 3;
  auto STAGE = [&](int bs, int k0) {
#pragma unroll
    for (int i = 0; i < 2; ++i) {
      int seg = wid * 2 + i;
      int r = sr + i * 16;
      int c = scp ^ ((r >> 1) & 3);
      char* base = smem + bs * 16384 + seg * 1024;
      glds16(yS + (size_t)(j0 + r) * C_ + k0 + c * 8, base);
      glds16(weS + (size_t)(o0 + r) * C_ + k0 + c * 8, base + 8192);
    }
  };
  f32x4 acc[4][4] = {};
  STAGE(0, 0);
  __syncthreads();
#pragma unroll
  for (int t = 0; t < 4; ++t) {
    if (t < 3) STAGE((t + 1) & 1, (t + 1) * 32);
    const char* ba = smem + (t & 1) * 16384;
    int sx = (quad ^ ((l15 >> 1) & 3)) * 16;
    short8 a[4], bfr[4];
#pragma unroll
    for (int mf = 0; mf < 4; ++mf)
      a[mf] = *reinterpret_cast<const short8*>(ba + (wm * 64 + mf * 16 + l15) * 64 + sx);
#pragma unroll
    for (int nf = 0; nf < 4; ++nf)
      bfr[nf] = *reinterpret_cast<const short8*>(ba + 8192 + (wn * 64 + nf * 16 + l15) * 64 + sx);
#pragma unroll
    for (int mf = 0; mf < 4; ++mf)
#pragma unroll
      for (int nf = 0; nf < 4; ++nf)
        acc[mf][nf] = __builtin_amdgcn_mfma_f32_16x16x32_bf16(a[mf], bfr[nf], acc[mf][nf], 0, 0, 0);
    __syncthreads();
  }
#pragma unroll
  for (int mf = 0; mf < 4; ++mf) {
    int jm = j0 + wm * 64 + mf * 16;
    int bb = jm / HW_;
#pragma unroll
    for (int nf = 0; nf < 4; ++nf) {
      int oc = wn * 64 + nf * 16 + l15;
      float g2 = 0.f;
#pragma unroll
      for (int r = 0; r < 4; ++r) { float ge = fast_gelu(acc[mf][nf][r]); g2 += ge * ge; }
      g2 += __shfl_xor(g2, 16, 64);
      g2 += __shfl_xor(g2, 32, 64);
      if (quad == 0) atomicAdd(&gx2[bb * CE_ + o0 + oc], g2);
    }
  }
}

// ---------------- K5: GRN per-batch scale ----------------
__global__ __launch_bounds__(512) void grn_scale_kernel(const float* __restrict__ gx2,
                                                        const float* __restrict__ gamma,
                                                        float* __restrict__ scale) {
  int b = blockIdx.x;
  int o = threadIdx.x;
  float gx = sqrtf(gx2[b * CE_ + o]);
  float s = wave_reduce_sum(gx);
  __shared__ float red[8];
  __shared__ float meansh;
  int lane = o & 63, wid = o >> 6;
  if (lane == 0) red[wid] = s;
  __syncthreads();
  if (o == 0) {
    float t = 0.f;
    for (int i = 0; i < 8; ++i) t += red[i];
    meansh = t * (1.0f / CE_);
  }
  __syncthreads();
  scale[b * CE_ + o] = 1.0f + gamma[o] * (gx / (meansh + EPS_));
}

// ---------------- K6: fused expand -> gelu*scale -> shrink + bias + residual ----------------
// 3 blocks/CU: A-tile (yT) in REGISTERS (one-time L3-hot gather, reused 4 chunks);
// LDS = B 32K + Es 16K (swizzled) = 48K. 4 barriers/chunk.
__global__ __launch_bounds__(256, 3) void fused_shrink(const bf16* __restrict__ yT,
                                                       const bf16* __restrict__ weB,
                                                       const bf16* __restrict__ wsB,
                                                       const float* __restrict__ scale,
                                                       const float* __restrict__ sb,
                                                       const float* __restrict__ x,
                                                       float* __restrict__ out) {
  int hw0 = blockIdx.x * 64;    // 49*64 = 3136 exact
  int b = blockIdx.y;
  int tid = threadIdx.x;
  int lane = tid & 63, wid = tid >> 6;
  int wm = wid >> 1, wn = wid & 1;
  int quad = lane >> 4, l15 = lane & 15;
  __shared__ __align__(16) char smem[49152];   // B @0 (32,768) | Es @32,768 (16,384); Ef aliases
  const short* yS  = reinterpret_cast<const short*>(yT) + (size_t)b * HW_ * C_;
  const short* weS = reinterpret_cast<const short*>(weB);
  const short* wsS = reinterpret_cast<const short*>(wsB);
  const float* scl = scale + b * CE_;
  // ---- one-time A-frag register loads (rows hw0 + wm*32+mf*16+l15, all K) ----
  short8 afr[4][2];
#pragma unroll
  for (int ks = 0; ks < 4; ++ks)
#pragma unroll
    for (int mf = 0; mf < 2; ++mf)
      afr[ks][mf] = *reinterpret_cast<const short8*>(
          yS + (size_t)(hw0 + wm * 32 + mf * 16 + l15) * C_ + ks * 32 + quad * 8);
  int lr4 = lane >> 4;          // row-within-4-row segment
  int lc16 = lane & 15;         // chunk position in 256B row
  unsigned short* Ep = reinterpret_cast<unsigned short*>(smem + 32768);
  f32x4 acc2[2][4] = {};
#pragma unroll 1
  for (int n = 0; n < 4; ++n) {
    int oc0 = n * 128;
    // ---- stage Bwe: weB rows oc0..oc0+127 (full K=128), source-swizzled ----
#pragma unroll
    for (int i = 0; i < 8; ++i) {
      int seg = wid * 8 + i;
      int r = seg * 4 + lr4;
      int csrc = lc16 ^ (r & 15);
      glds16(weS + (size_t)(oc0 + r) * C_ + csrc * 8, smem + seg * 1024);
    }
    __syncthreads();   // Bwe ready (vmcnt drain); prior-iter B/Es reads done via trailing bar
    // ---- expand: acc1 = A(regs) · Bwe^T ----
    f32x4 acc1[2][4] = {};
#pragma unroll
    for (int ks = 0; ks < 4; ++ks) {
      short8 bfr[4];
#pragma unroll
      for (int nf = 0; nf < 4; ++nf) {
        int row = wn * 64 + nf * 16 + l15;
        int cp = (ks * 4 + quad) ^ (row & 15);
        bfr[nf] = *reinterpret_cast<const short8*>(smem + row * 256 + cp * 16);
      }
#pragma unroll
      for (int mf = 0; mf < 2; ++mf)
#pragma unroll
        for (int nf = 0; nf < 4; ++nf)
          acc1[mf][nf] = __builtin_amdgcn_mfma_f32_16x16x32_bf16(afr[ks][mf], bfr[nf], acc1[mf][nf], 0, 0, 0);
    }
    __syncthreads();   // Bwe reads done -> B reusable
    // ---- epilogue-E: Es[row][ocl] = bf16(gelu(e)*scale), chunk-swizzled; stage Bws ----
#pragma unroll
    for (int nf = 0; nf < 4; ++nf) {
      int ocl = wn * 64 + nf * 16 + l15;
      float sc = scl[oc0 + ocl];
      int lchunk = ocl >> 3, lrem = ocl & 7;
#pragma unroll
      for (int mf = 0; mf < 2; ++mf) {
        int row0 = wm * 32 + mf * 16 + quad * 4;
#pragma unroll
        for (int r = 0; r < 4; ++r) {
          int row = row0 + r;
          Ep[row * 128 + ((lchunk ^ (row & 15)) << 3) + lrem] =
              f2bf_bits(fast_gelu(acc1[mf][nf][r]) * sc);
        }
      }
    }
#pragma unroll
    for (int i = 0; i < 8; ++i) {   // Bws: wsB rows c=0..127, o-slice [oc0, oc0+128)
      int seg = wid * 8 + i;
      int r = seg * 4 + lr4;
      int csrc = lc16 ^ (r & 15);
      glds16(wsS + (size_t)r * CE_ + oc0 + csrc * 8, smem + seg * 1024);
    }
    __syncthreads();   // Es ready (lgkm) + Bws ready (vmcnt)
    // ---- contract: acc2 += Es · Bws^T (K = this o-chunk of 128) ----
#pragma unroll
    for (int ks = 0; ks < 4; ++ks) {
      short8 a2[2], b2[4];
#pragma unroll
      for (int mf = 0; mf < 2; ++mf) {
        int row = wm * 32 + mf * 16 + l15;
        int cp = (ks * 4 + quad) ^ (row & 15);
        a2[mf] = *reinterpret_cast<const short8*>(smem + 32768 + row * 256 + cp * 16);
      }
#pragma unroll
      for (int nf = 0; nf < 4; ++nf) {
        int row = wn * 64 + nf * 16 + l15;
        int cp = (ks * 4 + quad) ^ (row & 15);
        b2[nf] = *reinterpret_cast<const short8*>(smem + row * 256 + cp * 16);
      }
#pragma unroll
      for (int mf = 0; mf < 2; ++mf)
#pragma unroll
        for (int nf = 0; nf < 4; ++nf)
          acc2[mf][nf] = __builtin_amdgcn_mfma_f32_16x16x32_bf16(a2[mf], b2[nf], acc2[mf][nf], 0, 0, 0);
    }
    __syncthreads();   // Es/Bws reads done before next chunk overwrites
  }
  // ---- final epilogue: single-phase f32 transpose (Ef[128 c][68] = 34,816 B), + sb + residual
  float (*Ef)[68] = reinterpret_cast<float(*)[68]>(&smem[0]);
#pragma unroll
  for (int mf = 0; mf < 2; ++mf) {
    int hwr = wm * 32 + mf * 16 + quad * 4;
#pragma unroll
    for (int nf = 0; nf < 4; ++nf)
      *reinterpret_cast<f32x4*>(&Ef[wn * 64 + nf * 16 + l15][hwr]) = acc2[mf][nf];
  }
  __syncthreads();
  // store: 128 c-rows x 64 hw (256B/row), 16 chunks(16B)/row -> 4 full rows / wave-instr
#pragma unroll
  for (int i = 0; i < 8; ++i) {
    int t = tid + 256 * i;
    int row = t >> 4, ch = t & 15;
    int hw = hw0 + ch * 4;
    size_t base = ((size_t)(b * C_ + row)) * HW_ + hw;
    float add = sb[row];
    f32x4 av = *reinterpret_cast<const f32x4*>(&Ef[row][ch * 4]);
    float4 xv = *reinterpret_cast<const float4*>(x + base);
    float4 ov;
    ov.x = av.x + add + xv.x;
    ov.y = av.y + add + xv.y;
    ov.z = av.z + add + xv.z;
    ov.w = av.w + add + xv.w;
    *reinterpret_cast<float4*>(out + base) = ov;
  }
}

extern "C" void kernel_launch(void* const* d_in, const int* in_sizes, int n_in,
                              void* d_out, int out_size, void* d_ws, size_t ws_size,
                              hipStream_t stream) {
  (void)in_sizes; (void)n_in; (void)out_size; (void)ws_size;
  const float* x        = (const float*)d_in[0];
  const float* w_fc1    = (const float*)d_in[1];
  const float* ln1_w    = (const float*)d_in[2];
  const float* ln1_b    = (const float*)d_in[3];
  const float* w_fc2    = (const float*)d_in[4];
  const float* ln2_w    = (const float*)d_in[5];
  const float* ln2_b    = (const float*)d_in[6];
  const float* w_expand = (const float*)d_in[7];
  const float* w_shrink = (const float*)d_in[8];
  const float* gamma    = (const float*)d_in[9];
  const float* beta     = (const float*)d_in[10];
  float* out = (float*)d_out;

  char* ws = (char*)d_ws;
  float* pooled = (float*)(ws + 0);
  float* dyn    = (float*)(ws + 16384);
  float* gx2    = (float*)(ws + 425984);
  float* scale  = (float*)(ws + 491520);
  float* sb     = (float*)(ws + 557056);
  bf16*  weB    = (bf16*)(ws + 557568);
  bf16*  wsB    = (bf16*)(ws + 688640);
  bf16*  yT     = (bf16*)(ws + 819712);
  bf16*  z      = (bf16*)(ws + 26509824);

  prep_all<<<4800, 256, 0, stream>>>(w_expand, w_shrink, beta, x, weB, wsB, gx2, sb, pooled);
  fc_kernel<<<B_, 256, 0, stream>>>(pooled, w_fc1, ln1_w, ln1_b, w_fc2, dyn);
  conv_kernel<<<B_ * C_, 256, 0, stream>>>(x, dyn, z);
  ln_kernel<<<dim3(49, B_), 256, 0, stream>>>(z, ln2_w, ln2_b, yT);
  gx2_pass<<<dim3(784, 4), 256, 0, stream>>>(yT, weB, gx2);
  grn_scale_kernel<<<B_, 512, 0, stream>>>(gx2, gamma, scale);
  fused_shrink<<<dim3(49, B_), 256, 0, stream>>>(yT, weB, wsB, scale, sb, x, out);
}

// Round 9
// 286.925 us; speedup vs baseline: 1.0626x; 1.0626x over previous
//
#include <hip/hip_runtime.h>
#include <hip/hip_bf16.h>

#define B_   32
#define C_   128
#define H_   56
#define W_   56
#define HW_  (H_*W_)
#define BHW_ (B_*HW_)        // 100352 = 784*128; 3136 = 49*64
#define K5_  5
#define KK_  25
#define CR_  32
#define CE_  512
#define EPS_ 1e-6f

typedef __hip_bfloat16 bf16;
typedef __attribute__((ext_vector_type(8))) short short8;   // 8 bf16 (4 VGPRs)
typedef __attribute__((ext_vector_type(4))) float f32x4;

// ---------- workspace layout (bytes) ----------
// pooled fp32 [B*C]        @ 0         (16,384)
// dyn    fp32 [B*C*25]     @ 16,384    (409,600)
// gx2    fp32 [B*CE]       @ 425,984   (65,536)
// sb     fp32 [C]          @ 557,056   (512)
// weB    bf16 [CE*C]       @ 557,568   (131,072)
// wsB    bf16 [C*CE]       @ 688,640   (131,072)
// yT     bf16 [BHW][C]     @ 819,712   (25,690,112)
//   sws bf16 [B][C][CE] (4,194,304 B) ALIASES head of yT (yT dead after expand)
// eT     bf16 [BHW][CE]    @ 26,509,824 (102,760,448)  (z aliases head of eT)

__device__ __forceinline__ float wave_reduce_sum(float v) {
#pragma unroll
  for (int off = 32; off > 0; off >>= 1) v += __shfl_down(v, off, 64);
  return v;
}
__device__ __forceinline__ float bf2f(unsigned short u) {
  return __uint_as_float(((unsigned)u) << 16);
}
__device__ __forceinline__ unsigned short f2bf_bits(float f) {
  bf16 h = __float2bfloat16(f);
  unsigned short u;
  __builtin_memcpy(&u, &h, 2);
  return u;
}
// sigmoid-form GELU: v * sigmoid(1.702 v)
__device__ __forceinline__ float fast_gelu(float v) {
  float t = __expf(-1.702f * v);
  return v * __builtin_amdgcn_rcpf(1.0f + t);
}
// async global->LDS, 16B per lane; LDS dest = wave-uniform base + lane*16
__device__ __forceinline__ void glds16(const void* g, void* l) {
  __builtin_amdgcn_global_load_lds(
      (const __attribute__((address_space(1))) unsigned int*)g,
      (__attribute__((address_space(3))) unsigned int*)l, 16, 0, 0);
}

// ---------------- K0: merged prep (weights->bf16, gx2=0, sb, pool) ----------------
// blocks 0..575: convert/zero; 576..703: sb[c]; 704..4799: pool (bc = bx-704)
__global__ __launch_bounds__(256) void prep_all(const float* __restrict__ we,
                                                const float* __restrict__ ws,
                                                const float* __restrict__ beta,
                                                const float* __restrict__ x,
                                                bf16* __restrict__ weB,
                                                bf16* __restrict__ wsB,
                                                float* __restrict__ gx2,
                                                float* __restrict__ sb,
                                                float* __restrict__ pooled) {
  int bx = blockIdx.x;
  if (bx < 576) {
    int i = bx * 256 + threadIdx.x;
    if (i < CE_ * C_)          weB[i] = __float2bfloat16(we[i]);
    else if (i < 2 * CE_ * C_) wsB[i - CE_ * C_] = __float2bfloat16(ws[i - CE_ * C_]);
    else                       gx2[i - 2 * CE_ * C_] = 0.f;
  } else if (bx < 704) {
    int c = bx - 576;
    const float* wp = ws + (size_t)c * CE_;
    float acc = 0.f;
    for (int o = threadIdx.x; o < CE_; o += 256) acc += wp[o] * beta[o];
    acc = wave_reduce_sum(acc);
    __shared__ float red[4];
    int lane = threadIdx.x & 63, wid = threadIdx.x >> 6;
    if (lane == 0) red[wid] = acc;
    __syncthreads();
    if (threadIdx.x == 0) sb[c] = red[0] + red[1] + red[2] + red[3];
  } else {
    int bc = bx - 704;
    const float4* xp4 = reinterpret_cast<const float4*>(x + (size_t)bc * HW_);
    float s = 0.f;
    for (int i = threadIdx.x; i < 784; i += 256) {
      float4 v = xp4[i];
      s += (v.x + v.y) + (v.z + v.w);
    }
    s = wave_reduce_sum(s);
    __shared__ float redp[4];
    int lane = threadIdx.x & 63, wid = threadIdx.x >> 6;
    if (lane == 0) redp[wid] = s;
    __syncthreads();
    if (threadIdx.x == 0) pooled[bc] = (redp[0] + redp[1] + redp[2] + redp[3]) * (1.0f / HW_);
  }
}

// ---------------- K2: fc1 -> LN1 -> fc2 (dyn weights) ----------------
__global__ __launch_bounds__(256) void fc_kernel(const float* __restrict__ pooled,
                                                 const float* __restrict__ w_fc1,
                                                 const float* __restrict__ ln1_w,
                                                 const float* __restrict__ ln1_b,
                                                 const float* __restrict__ w_fc2,
                                                 float* __restrict__ dyn) {
  int b = blockIdx.x;
  int tid = threadIdx.x;
  __shared__ float sp[C_];
  __shared__ float sh[CR_];
  __shared__ float shn[CR_];
  __shared__ float stats[2];
  if (tid < C_) sp[tid] = pooled[b * C_ + tid];
  __syncthreads();
  if (tid < CR_) {
    float acc = 0.f;
    const float* wr = w_fc1 + tid * C_;
#pragma unroll 4
    for (int c = 0; c < C_; ++c) acc += sp[c] * wr[c];
    sh[tid] = acc;
  }
  __syncthreads();
  if (tid == 0) {
    float u = 0.f;
    for (int j = 0; j < CR_; ++j) u += sh[j];
    u *= (1.0f / CR_);
    float v = 0.f;
    for (int j = 0; j < CR_; ++j) { float d = sh[j] - u; v += d * d; }
    v *= (1.0f / CR_);
    stats[0] = u;
    stats[1] = rsqrtf(v + EPS_);
  }
  __syncthreads();
  if (tid < CR_) shn[tid] = (sh[tid] - stats[0]) * stats[1] * ln1_w[tid] + ln1_b[tid];
  __syncthreads();
  for (int i = tid; i < C_ * KK_; i += 256) {
    const float* wr = w_fc2 + i * CR_;
    float acc = 0.f;
#pragma unroll
    for (int j = 0; j < CR_; ++j) acc += shn[j] * wr[j];
    dyn[b * (C_ * KK_) + i] = acc;
  }
}

// ---------------- K3a: dynamic depthwise 5x5 conv -> z (bf16, [b][c][hw]) ----------------
__global__ __launch_bounds__(256) void conv_kernel(const float* __restrict__ x,
                                                   const float* __restrict__ dyn,
                                                   bf16* __restrict__ z) {
  int bc = blockIdx.x;
  int b = bc >> 7;
  int c = bc & 127;
  int tid = threadIdx.x;
  __shared__ float xs[(H_ + 4) * 64];   // rows -2..57 at (r+2)*64; 15,360 B
  __shared__ float wks[KK_];
  {  // zero halo rows 0,1,58,59 (full) — 4*64 = 256 = blockDim
    int r = tid >> 6;
    int rr = (r < 2) ? r : (56 + r);
    xs[rr * 64 + (tid & 63)] = 0.f;
  }
  if (tid < 224) {  // zero halo cols 0,1,58,59 of data rows 2..57
    int r = tid >> 2, q = tid & 3;
    int col = (q < 2) ? q : (56 + q);
    xs[(r + 2) * 64 + col] = 0.f;
  }
  if (tid < KK_) wks[tid] = dyn[b * (C_ * KK_) + c * KK_ + tid];
  const float4* xp4 = reinterpret_cast<const float4*>(x + (size_t)bc * HW_);
  for (int i = tid; i < 784; i += 256) {
    float4 v = xp4[i];
    int h = i / 14, w4 = (i % 14) * 4;
    float* dst = &xs[(h + 2) * 64 + 2 + w4];
    dst[0] = v.x; dst[1] = v.y; dst[2] = v.z; dst[3] = v.w;
  }
  __syncthreads();
  float wr[KK_];
#pragma unroll
  for (int j = 0; j < KK_; ++j) wr[j] = wks[j];
  for (int g = tid; g < 784; g += 256) {
    int h = g / 14;
    int w4 = (g % 14) * 4;
    float a0 = 0.f, a1 = 0.f, a2 = 0.f, a3 = 0.f;
#pragma unroll
    for (int dh = 0; dh < K5_; ++dh) {
      const float* row = &xs[(h + dh) * 64 + w4];   // padded row h+dh-2
      float4 va = *reinterpret_cast<const float4*>(row);
      float4 vb = *reinterpret_cast<const float4*>(row + 4);
      float v0 = va.x, v1 = va.y, v2 = va.z, v3 = va.w;
      float v4 = vb.x, v5 = vb.y, v6 = vb.z, v7 = vb.w;
      float u0 = wr[dh * 5 + 0], u1 = wr[dh * 5 + 1], u2 = wr[dh * 5 + 2];
      float u3 = wr[dh * 5 + 3], u4 = wr[dh * 5 + 4];
      a0 += v0 * u0 + v1 * u1 + v2 * u2 + v3 * u3 + v4 * u4;
      a1 += v1 * u0 + v2 * u1 + v3 * u2 + v4 * u3 + v5 * u4;
      a2 += v2 * u0 + v3 * u1 + v4 * u2 + v5 * u3 + v6 * u4;
      a3 += v3 * u0 + v4 * u1 + v5 * u2 + v6 * u3 + v7 * u4;
    }
    size_t base = (size_t)bc * HW_ + h * W_ + w4;
    ushort4 pk = make_ushort4(f2bf_bits(a0), f2bf_bits(a1), f2bf_bits(a2), f2bf_bits(a3));
    *reinterpret_cast<ushort4*>(reinterpret_cast<unsigned short*>(z) + base) = pk;
  }
}

// ---------------- K3b: channel LN over z -> yT (bf16, [j][c]); vectorized loads ----------------
__global__ __launch_bounds__(256) void ln_kernel(const bf16* __restrict__ z,
                                                 const float* __restrict__ ln2_w,
                                                 const float* __restrict__ ln2_b,
                                                 bf16* __restrict__ yT) {
  int hw0 = blockIdx.x * 64;
  int b = blockIdx.y;
  int tid = threadIdx.x;
  int wq = tid & 63;
  int cq = tid >> 6;
  __shared__ unsigned short zt[C_][64];     // 16 KB
  __shared__ unsigned short yt[64][136];    // 17.4 KB transpose buffer (rows 16B-aligned)
  __shared__ float redS[4][64];
  __shared__ float redQ[4][64];
  __shared__ float meanArr[64];
  __shared__ float invArr[64];
  const unsigned short* zp = reinterpret_cast<const unsigned short*>(z);
#pragma unroll
  for (int i = 0; i < 4; ++i) {
    int t = tid + 256 * i;
    int c = t >> 3, ch = t & 7;
    int4 v = *reinterpret_cast<const int4*>(zp + ((size_t)(b * C_ + c)) * HW_ + hw0 + ch * 8);
    *reinterpret_cast<int4*>(&zt[c][ch * 8]) = v;
  }
  __syncthreads();
  float s = 0.f, q = 0.f;
#pragma unroll 4
  for (int k = 0; k < 32; ++k) {
    float v = bf2f(zt[cq * 32 + k][wq]);
    s += v;
    q += v * v;
  }
  redS[cq][wq] = s;
  redQ[cq][wq] = q;
  __syncthreads();
  if (cq == 0) {
    float ss = redS[0][wq] + redS[1][wq] + redS[2][wq] + redS[3][wq];
    float qq = redQ[0][wq] + redQ[1][wq] + redQ[2][wq] + redQ[3][wq];
    float m = ss * (1.0f / C_);
    float var = qq * (1.0f / C_) - m * m;
    meanArr[wq] = m;
    invArr[wq] = rsqrtf(fmaxf(var, 0.f) + EPS_);
  }
  __syncthreads();
  float m = meanArr[wq], iv = invArr[wq];
#pragma unroll
  for (int g = 0; g < 4; ++g) {
    unsigned short pk[8];
#pragma unroll
    for (int i = 0; i < 8; ++i) {
      int c = cq * 32 + g * 8 + i;
      float v = bf2f(zt[c][wq]);
      pk[i] = f2bf_bits((v - m) * iv * ln2_w[c] + ln2_b[c]);
    }
    int4 t;
    __builtin_memcpy(&t, pk, 16);
    *reinterpret_cast<int4*>(&yt[wq][cq * 32 + g * 8]) = t;
  }
  __syncthreads();
  unsigned short* yp = reinterpret_cast<unsigned short*>(yT);
#pragma unroll
  for (int i = 0; i < 4; ++i) {
    int t = tid + 256 * i;
    int row = t >> 4, ch = t & 15;
    int4 v = *reinterpret_cast<const int4*>(&yt[row][ch * 8]);
    *reinterpret_cast<int4*>(yp + ((size_t)(b * HW_ + hw0 + row)) * C_ + ch * 8) = v;
  }
}

// ---------------- K4: expand MFMA GEMM + GELU + gx2 + eT ----------------
// r5 staging (glds16 dbuf, swizzled) + Es chunk-swizzled [128][128] -> LDS exactly 32 KB
// -> 5 blocks/CU (was 4 at 34.8 KB).
__global__ __launch_bounds__(256, 5) void expand_mfma(const bf16* __restrict__ yT,
                                                      const bf16* __restrict__ weB,
                                                      bf16* __restrict__ eT,
                                                      float* __restrict__ gx2) {
  int j0 = blockIdx.x * 128;    // 784 tiles (fast dim keeps yT L3-hot)
  int o0 = blockIdx.y * 128;    // 4 tiles
  int tid = threadIdx.x;
  int lane = tid & 63, wid = tid >> 6;
  int wm = wid >> 1, wn = wid & 1;
  int quad = lane >> 4, l15 = lane & 15;
  __shared__ __align__(16) char smem[32768];   // dbuf: buf t @ (t&1)*16384 {A 8K, B 8K}; Es union
  const short* yS = reinterpret_cast<const short*>(yT);
  const short* weS = reinterpret_cast<const short*>(weB);
  int sr = (wid * 2) * 16 + (lane >> 2);
  int scp = lane & 3;
  auto STAGE = [&](int bs, int k0) {
#pragma unroll
    for (int i = 0; i < 2; ++i) {
      int seg = wid * 2 + i;
      int r = sr + i * 16;
      int c = scp ^ ((r >> 1) & 3);
      char* base = smem + bs * 16384 + seg * 1024;
      glds16(yS + (size_t)(j0 + r) * C_ + k0 + c * 8, base);
      glds16(weS + (size_t)(o0 + r) * C_ + k0 + c * 8, base + 8192);
    }
  };
  f32x4 acc[4][4] = {};
  STAGE(0, 0);
  __syncthreads();
#pragma unroll
  for (int t = 0; t < 4; ++t) {
    if (t < 3) STAGE((t + 1) & 1, (t + 1) * 32);
    const char* ba = smem + (t & 1) * 16384;
    int sx = (quad ^ ((l15 >> 1) & 3)) * 16;
    short8 a[4], bfr[4];
#pragma unroll
    for (int mf = 0; mf < 4; ++mf)
      a[mf] = *reinterpret_cast<const short8*>(ba + (wm * 64 + mf * 16 + l15) * 64 + sx);
#pragma unroll
    for (int nf = 0; nf < 4; ++nf)
      bfr[nf] = *reinterpret_cast<const short8*>(ba + 8192 + (wn * 64 + nf * 16 + l15) * 64 + sx);
#pragma unroll
    for (int mf = 0; mf < 4; ++mf)
#pragma unroll
      for (int nf = 0; nf < 4; ++nf)
        acc[mf][nf] = __builtin_amdgcn_mfma_f32_16x16x32_bf16(a[mf], bfr[nf], acc[mf][nf], 0, 0, 0);
    __syncthreads();   // drains vmcnt(0): next-chunk stage complete; this-buf reads done
  }
  // epilogue: GELU + gx2 from regs, Es chunk-swizzled [128 rows][128 o] (32 KB, bufs dead)
  unsigned short* Ep = reinterpret_cast<unsigned short*>(smem);
#pragma unroll
  for (int mf = 0; mf < 4; ++mf) {
    int jm = j0 + wm * 64 + mf * 16;       // 16-aligned -> single b per m-frag
    int bb = jm / HW_;
    int jrow = wm * 64 + mf * 16 + quad * 4;
#pragma unroll
    for (int nf = 0; nf < 4; ++nf) {
      int oc = wn * 64 + nf * 16 + l15;
      int lchunk = oc >> 3, lrem = oc & 7;
      float g2 = 0.f;
#pragma unroll
      for (int r = 0; r < 4; ++r) {
        float ge = fast_gelu(acc[mf][nf][r]);
        g2 += ge * ge;
        int row = jrow + r;
        Ep[row * 128 + ((lchunk ^ (row & 15)) << 3) + lrem] = f2bf_bits(ge);
      }
      g2 += __shfl_xor(g2, 16, 64);
      g2 += __shfl_xor(g2, 32, 64);
      if (quad == 0) atomicAdd(&gx2[bb * CE_ + o0 + oc], g2);
    }
  }
  __syncthreads();
  unsigned short* eP = reinterpret_cast<unsigned short*>(eT);
#pragma unroll
  for (int i = 0; i < 8; ++i) {   // 128 rows x 16 chunks(16B): 4 full rows / wave-instr
    int t = tid + 256 * i;
    int row = t >> 4, ch = t & 15;
    int4 v = *reinterpret_cast<const int4*>(Ep + row * 128 + ((ch ^ (row & 15)) << 3));
    *reinterpret_cast<int4*>(eP + (size_t)(j0 + row) * CE_ + o0 + ch * 8) = v;
  }
}

// ---------------- K5: GRN scale + ws scaling, merged (per-block redundant reduction) ----------------
// block (c,b): recompute mean_o sqrt(gx2[b][o]) from L2-hot gx2 (cheap), then
// sws[b][c][o] = ws[c][o] * (1 + gamma[o]*gx[o]/mean).
__global__ __launch_bounds__(256) void grn_scale_ws(const float* __restrict__ gx2,
                                                    const float* __restrict__ gamma,
                                                    const float* __restrict__ ws,
                                                    bf16* __restrict__ sws) {
  int c = blockIdx.x;
  int b = blockIdx.y;
  int tid = threadIdx.x;
  __shared__ float gxs[CE_];
  __shared__ float red[4];
  __shared__ float invm;
  const float* gp = gx2 + b * CE_;
  float g0 = sqrtf(gp[tid]);
  float g1 = sqrtf(gp[tid + 256]);
  gxs[tid] = g0;
  gxs[tid + 256] = g1;
  float s = wave_reduce_sum(g0 + g1);
  int lane = tid & 63, wid = tid >> 6;
  if (lane == 0) red[wid] = s;
  __syncthreads();
  if (tid == 0) invm = 1.0f / ((red[0] + red[1] + red[2] + red[3]) * (1.0f / CE_) + EPS_);
  __syncthreads();
  float im = invm;
  const float* wp = ws + (size_t)c * CE_;
  bf16* op = sws + ((size_t)(b * C_ + c)) * CE_;
#pragma unroll
  for (int i = tid; i < CE_; i += 256) {
    float sc = 1.0f + gamma[i] * (gxs[i] * im);
    op[i] = __float2bfloat16(wp[i] * sc);
  }
}

// ---------------- K6: shrink MFMA GEMM + bias + residual (r6 exact) ----------------
// 64-hw tiles, grid (49,B) EXACT. k=64 glds dbuf (A 8K + B 16K per buf, 48 KB total)
// -> 3 blocks/CU. Swizzle c^=r&7 on source and read. Single-phase epilogue.
__global__ __launch_bounds__(256, 3) void shrink_mfma(const bf16* __restrict__ eT,
                                                      const bf16* __restrict__ sws,
                                                      const float* __restrict__ sb,
                                                      const float* __restrict__ x,
                                                      float* __restrict__ out) {
  int hw0 = blockIdx.x * 64;    // 49*64 = 3136 exact
  int b = blockIdx.y;
  int tid = threadIdx.x;
  int lane = tid & 63, wid = tid >> 6;
  int wm = wid >> 1, wn = wid & 1;
  int quad = lane >> 4, l15 = lane & 15;
  __shared__ __align__(16) char smem[49152];   // dbuf @ (t&1)*24576 {A 8K, B 16K}; Ef union
  const short* eS  = reinterpret_cast<const short*>(eT) + (size_t)b * HW_ * CE_;
  const short* wsS = reinterpret_cast<const short*>(sws) + (size_t)b * C_ * CE_;
  int lr = lane >> 3;                           // row-within-segment
  int lc = lane & 7;                            // chunk position in 128B row
  auto STAGE = [&](int bs, int k0) {
    char* base = smem + bs * 24576;
#pragma unroll
    for (int i = 0; i < 2; ++i) {               // A: 8 segs of 8 rows (64 rows)
      int seg = wid * 2 + i;
      int r = seg * 8 + lr;
      int c = lc ^ (r & 7);
      glds16(eS + (size_t)(hw0 + r) * CE_ + k0 + c * 8, base + seg * 1024);
    }
#pragma unroll
    for (int i = 0; i < 4; ++i) {               // B: 16 segs of 8 rows (128 rows)
      int seg = wid * 4 + i;
      int r = seg * 8 + lr;
      int c = lc ^ (r & 7);
      glds16(wsS + (size_t)r * CE_ + k0 + c * 8, base + 8192 + seg * 1024);
    }
  };
  f32x4 acc[2][4] = {};
  STAGE(0, 0);
  __syncthreads();
#pragma unroll 1
  for (int t = 0; t < 8; ++t) {
    if (t < 7) STAGE((t + 1) & 1, (t + 1) * 64);
    const char* ba = smem + (t & 1) * 24576;
#pragma unroll
    for (int ks = 0; ks < 2; ++ks) {
      short8 a[2], bfr[4];
#pragma unroll
      for (int mf = 0; mf < 2; ++mf) {
        int row = wm * 32 + mf * 16 + l15;
        int cp = (ks * 4 + quad) ^ (row & 7);
        a[mf] = *reinterpret_cast<const short8*>(ba + row * 128 + cp * 16);
      }
#pragma unroll
      for (int nf = 0; nf < 4; ++nf) {
        int row = wn * 64 + nf * 16 + l15;
        int cp = (ks * 4 + quad) ^ (row & 7);
        bfr[nf] = *reinterpret_cast<const short8*>(ba + 8192 + row * 128 + cp * 16);
      }
#pragma unroll
      for (int mf = 0; mf < 2; ++mf)
#pragma unroll
        for (int nf = 0; nf < 4; ++nf)
          acc[mf][nf] = __builtin_amdgcn_mfma_f32_16x16x32_bf16(a[mf], bfr[nf], acc[mf][nf], 0, 0, 0);
    }
    __syncthreads();
  }
  // single-phase f32 transpose epilogue: Ef[128 c][68] (34.8 KB, bufs dead), + sb + residual
  float (*Ef)[68] = reinterpret_cast<float(*)[68]>(&smem[0]);
#pragma unroll
  for (int mf = 0; mf < 2; ++mf) {
    int hwr = wm * 32 + mf * 16 + quad * 4;
#pragma unroll
    for (int nf = 0; nf < 4; ++nf)
      *reinterpret_cast<f32x4*>(&Ef[wn * 64 + nf * 16 + l15][hwr]) = acc[mf][nf];
  }
  __syncthreads();
  // store: 128 c-rows x 64 hw (256B/row), 16 chunks(16B)/row -> 4 full rows / wave-instr
#pragma unroll
  for (int i = 0; i < 8; ++i) {
    int t = tid + 256 * i;
    int row = t >> 4, ch = t & 15;
    int hw = hw0 + ch * 4;
    size_t base = ((size_t)(b * C_ + row)) * HW_ + hw;
    float add = sb[row];
    f32x4 av = *reinterpret_cast<const f32x4*>(&Ef[row][ch * 4]);
    float4 xv = *reinterpret_cast<const float4*>(x + base);
    float4 ov;
    ov.x = av.x + add + xv.x;
    ov.y = av.y + add + xv.y;
    ov.z = av.z + add + xv.z;
    ov.w = av.w + add + xv.w;
    *reinterpret_cast<float4*>(out + base) = ov;
  }
}

extern "C" void kernel_launch(void* const* d_in, const int* in_sizes, int n_in,
                              void* d_out, int out_size, void* d_ws, size_t ws_size,
                              hipStream_t stream) {
  (void)in_sizes; (void)n_in; (void)out_size; (void)ws_size;
  const float* x        = (const float*)d_in[0];
  const float* w_fc1    = (const float*)d_in[1];
  const float* ln1_w    = (const float*)d_in[2];
  const float* ln1_b    = (const float*)d_in[3];
  const float* w_fc2    = (const float*)d_in[4];
  const float* ln2_w    = (const float*)d_in[5];
  const float* ln2_b    = (const float*)d_in[6];
  const float* w_expand = (const float*)d_in[7];
  const float* w_shrink = (const float*)d_in[8];
  const float* gamma    = (const float*)d_in[9];
  const float* beta     = (const float*)d_in[10];
  float* out = (float*)d_out;

  char* ws = (char*)d_ws;
  float* pooled = (float*)(ws + 0);
  float* dyn    = (float*)(ws + 16384);
  float* gx2    = (float*)(ws + 425984);
  float* sb     = (float*)(ws + 557056);
  bf16*  weB    = (bf16*)(ws + 557568);
  bf16*  wsB    = (bf16*)(ws + 688640);
  bf16*  yT     = (bf16*)(ws + 819712);
  bf16*  sws    = (bf16*)(ws + 819712);   // alias: yT dead after expand_mfma
  bf16*  eT     = (bf16*)(ws + 26509824);
  bf16*  z      = eT;                     // alias: z dead before expand_mfma writes eT

  prep_all<<<4800, 256, 0, stream>>>(w_expand, w_shrink, beta, x, weB, wsB, gx2, sb, pooled);
  fc_kernel<<<B_, 256, 0, stream>>>(pooled, w_fc1, ln1_w, ln1_b, w_fc2, dyn);
  conv_kernel<<<B_ * C_, 256, 0, stream>>>(x, dyn, z);
  ln_kernel<<<dim3(49, B_), 256, 0, stream>>>(z, ln2_w, ln2_b, yT);
  expand_mfma<<<dim3(784, 4), 256, 0, stream>>>(yT, weB, eT, gx2);
  grn_scale_ws<<<dim3(C_, B_), 256, 0, stream>>>(gx2, gamma, w_shrink, sws);
  shrink_mfma<<<dim3(49, B_), 256, 0, stream>>>(eT, sws, sb, x, out);
}

// Round 10
// 264.842 us; speedup vs baseline: 1.1512x; 1.0834x over previous
//
#include <hip/hip_runtime.h>
#include <hip/hip_bf16.h>

#define B_   32
#define C_   128
#define H_   56
#define W_   56
#define HW_  (H_*W_)
#define BHW_ (B_*HW_)        // 100352 = 784*128; 3136 = 49*64
#define K5_  5
#define KK_  25
#define CR_  32
#define CE_  512
#define EPS_ 1e-6f

typedef __hip_bfloat16 bf16;
typedef __attribute__((ext_vector_type(8))) short short8;   // 8 bf16 (4 VGPRs)
typedef __attribute__((ext_vector_type(4))) float f32x4;

// ---------- workspace layout (bytes) ----------
// pooled fp32 [B*C]        @ 0         (16,384)
// dyn    fp32 [B*C*25]     @ 16,384    (409,600)
// gx2    fp32 [B*CE]       @ 425,984   (65,536)
// sb     fp32 [C]          @ 557,056   (512)
// weB    bf16 [CE*C]       @ 557,568   (131,072)
// wsB    bf16 [C*CE]       @ 688,640   (131,072)
// yT     bf16 [BHW][C]     @ 819,712   (25,690,112)
//   sws bf16 [B][C][CE] (4,194,304 B) ALIASES head of yT (yT dead after expand)
// eT     bf16 [BHW][CE]    @ 26,509,824 (102,760,448)  (z aliases head of eT)

__device__ __forceinline__ float wave_reduce_sum(float v) {
#pragma unroll
  for (int off = 32; off > 0; off >>= 1) v += __shfl_down(v, off, 64);
  return v;
}
__device__ __forceinline__ float bf2f(unsigned short u) {
  return __uint_as_float(((unsigned)u) << 16);
}
__device__ __forceinline__ unsigned short f2bf_bits(float f) {
  bf16 h = __float2bfloat16(f);
  unsigned short u;
  __builtin_memcpy(&u, &h, 2);
  return u;
}
// sigmoid-form GELU: v * sigmoid(1.702 v)
__device__ __forceinline__ float fast_gelu(float v) {
  float t = __expf(-1.702f * v);
  return v * __builtin_amdgcn_rcpf(1.0f + t);
}
// async global->LDS, 16B per lane; LDS dest = wave-uniform base + lane*16
__device__ __forceinline__ void glds16(const void* g, void* l) {
  __builtin_amdgcn_global_load_lds(
      (const __attribute__((address_space(1))) unsigned int*)g,
      (__attribute__((address_space(3))) unsigned int*)l, 16, 0, 0);
}

// ---------------- K0: merged prep (weights->bf16, gx2=0, sb, pool) ----------------
// blocks 0..575: convert/zero; 576..703: sb[c]; 704..4799: pool (bc = bx-704)
__global__ __launch_bounds__(256) void prep_all(const float* __restrict__ we,
                                                const float* __restrict__ ws,
                                                const float* __restrict__ beta,
                                                const float* __restrict__ x,
                                                bf16* __restrict__ weB,
                                                bf16* __restrict__ wsB,
                                                float* __restrict__ gx2,
                                                float* __restrict__ sb,
                                                float* __restrict__ pooled) {
  int bx = blockIdx.x;
  if (bx < 576) {
    int i = bx * 256 + threadIdx.x;
    if (i < CE_ * C_)          weB[i] = __float2bfloat16(we[i]);
    else if (i < 2 * CE_ * C_) wsB[i - CE_ * C_] = __float2bfloat16(ws[i - CE_ * C_]);
    else                       gx2[i - 2 * CE_ * C_] = 0.f;
  } else if (bx < 704) {
    int c = bx - 576;
    const float* wp = ws + (size_t)c * CE_;
    float acc = 0.f;
    for (int o = threadIdx.x; o < CE_; o += 256) acc += wp[o] * beta[o];
    acc = wave_reduce_sum(acc);
    __shared__ float red[4];
    int lane = threadIdx.x & 63, wid = threadIdx.x >> 6;
    if (lane == 0) red[wid] = acc;
    __syncthreads();
    if (threadIdx.x == 0) sb[c] = red[0] + red[1] + red[2] + red[3];
  } else {
    int bc = bx - 704;
    const float4* xp4 = reinterpret_cast<const float4*>(x + (size_t)bc * HW_);
    float s = 0.f;
    for (int i = threadIdx.x; i < 784; i += 256) {
      float4 v = xp4[i];
      s += (v.x + v.y) + (v.z + v.w);
    }
    s = wave_reduce_sum(s);
    __shared__ float redp[4];
    int lane = threadIdx.x & 63, wid = threadIdx.x >> 6;
    if (lane == 0) redp[wid] = s;
    __syncthreads();
    if (threadIdx.x == 0) pooled[bc] = (redp[0] + redp[1] + redp[2] + redp[3]) * (1.0f / HW_);
  }
}

// ---------------- K2: fc1 -> LN1 -> fc2 (dyn weights) ----------------
__global__ __launch_bounds__(256) void fc_kernel(const float* __restrict__ pooled,
                                                 const float* __restrict__ w_fc1,
                                                 const float* __restrict__ ln1_w,
                                                 const float* __restrict__ ln1_b,
                                                 const float* __restrict__ w_fc2,
                                                 float* __restrict__ dyn) {
  int b = blockIdx.x;
  int tid = threadIdx.x;
  __shared__ float sp[C_];
  __shared__ float sh[CR_];
  __shared__ float shn[CR_];
  __shared__ float stats[2];
  if (tid < C_) sp[tid] = pooled[b * C_ + tid];
  __syncthreads();
  if (tid < CR_) {
    float acc = 0.f;
    const float* wr = w_fc1 + tid * C_;
#pragma unroll 4
    for (int c = 0; c < C_; ++c) acc += sp[c] * wr[c];
    sh[tid] = acc;
  }
  __syncthreads();
  if (tid == 0) {
    float u = 0.f;
    for (int j = 0; j < CR_; ++j) u += sh[j];
    u *= (1.0f / CR_);
    float v = 0.f;
    for (int j = 0; j < CR_; ++j) { float d = sh[j] - u; v += d * d; }
    v *= (1.0f / CR_);
    stats[0] = u;
    stats[1] = rsqrtf(v + EPS_);
  }
  __syncthreads();
  if (tid < CR_) shn[tid] = (sh[tid] - stats[0]) * stats[1] * ln1_w[tid] + ln1_b[tid];
  __syncthreads();
  for (int i = tid; i < C_ * KK_; i += 256) {
    const float* wr = w_fc2 + i * CR_;
    float acc = 0.f;
#pragma unroll
    for (int j = 0; j < CR_; ++j) acc += shn[j] * wr[j];
    dyn[b * (C_ * KK_) + i] = acc;
  }
}

// ---------------- K3a: dynamic depthwise 5x5 conv -> z (bf16, [b][c][hw]) ----------------
__global__ __launch_bounds__(256) void conv_kernel(const float* __restrict__ x,
                                                   const float* __restrict__ dyn,
                                                   bf16* __restrict__ z) {
  int bc = blockIdx.x;
  int b = bc >> 7;
  int c = bc & 127;
  int tid = threadIdx.x;
  __shared__ float xs[(H_ + 4) * 64];   // rows -2..57 at (r+2)*64; 15,360 B
  __shared__ float wks[KK_];
  {  // zero halo rows 0,1,58,59 (full) — 4*64 = 256 = blockDim
    int r = tid >> 6;
    int rr = (r < 2) ? r : (56 + r);
    xs[rr * 64 + (tid & 63)] = 0.f;
  }
  if (tid < 224) {  // zero halo cols 0,1,58,59 of data rows 2..57
    int r = tid >> 2, q = tid & 3;
    int col = (q < 2) ? q : (56 + q);
    xs[(r + 2) * 64 + col] = 0.f;
  }
  if (tid < KK_) wks[tid] = dyn[b * (C_ * KK_) + c * KK_ + tid];
  const float4* xp4 = reinterpret_cast<const float4*>(x + (size_t)bc * HW_);
  for (int i = tid; i < 784; i += 256) {
    float4 v = xp4[i];
    int h = i / 14, w4 = (i % 14) * 4;
    float* dst = &xs[(h + 2) * 64 + 2 + w4];
    dst[0] = v.x; dst[1] = v.y; dst[2] = v.z; dst[3] = v.w;
  }
  __syncthreads();
  float wr[KK_];
#pragma unroll
  for (int j = 0; j < KK_; ++j) wr[j] = wks[j];
  for (int g = tid; g < 784; g += 256) {
    int h = g / 14;
    int w4 = (g % 14) * 4;
    float a0 = 0.f, a1 = 0.f, a2 = 0.f, a3 = 0.f;
#pragma unroll
    for (int dh = 0; dh < K5_; ++dh) {
      const float* row = &xs[(h + dh) * 64 + w4];   // padded row h+dh-2
      float4 va = *reinterpret_cast<const float4*>(row);
      float4 vb = *reinterpret_cast<const float4*>(row + 4);
      float v0 = va.x, v1 = va.y, v2 = va.z, v3 = va.w;
      float v4 = vb.x, v5 = vb.y, v6 = vb.z, v7 = vb.w;
      float u0 = wr[dh * 5 + 0], u1 = wr[dh * 5 + 1], u2 = wr[dh * 5 + 2];
      float u3 = wr[dh * 5 + 3], u4 = wr[dh * 5 + 4];
      a0 += v0 * u0 + v1 * u1 + v2 * u2 + v3 * u3 + v4 * u4;
      a1 += v1 * u0 + v2 * u1 + v3 * u2 + v4 * u3 + v5 * u4;
      a2 += v2 * u0 + v3 * u1 + v4 * u2 + v5 * u3 + v6 * u4;
      a3 += v3 * u0 + v4 * u1 + v5 * u2 + v6 * u3 + v7 * u4;
    }
    size_t base = (size_t)bc * HW_ + h * W_ + w4;
    ushort4 pk = make_ushort4(f2bf_bits(a0), f2bf_bits(a1), f2bf_bits(a2), f2bf_bits(a3));
    *reinterpret_cast<ushort4*>(reinterpret_cast<unsigned short*>(z) + base) = pk;
  }
}

// ---------------- K3b: channel LN over z -> yT (bf16, [j][c]); vectorized loads ----------------
__global__ __launch_bounds__(256) void ln_kernel(const bf16* __restrict__ z,
                                                 const float* __restrict__ ln2_w,
                                                 const float* __restrict__ ln2_b,
                                                 bf16* __restrict__ yT) {
  int hw0 = blockIdx.x * 64;
  int b = blockIdx.y;
  int tid = threadIdx.x;
  int wq = tid & 63;
  int cq = tid >> 6;
  __shared__ unsigned short zt[C_][64];     // 16 KB
  __shared__ unsigned short yt[64][136];    // 17.4 KB transpose buffer (rows 16B-aligned)
  __shared__ float redS[4][64];
  __shared__ float redQ[4][64];
  __shared__ float meanArr[64];
  __shared__ float invArr[64];
  const unsigned short* zp = reinterpret_cast<const unsigned short*>(z);
#pragma unroll
  for (int i = 0; i < 4; ++i) {
    int t = tid + 256 * i;
    int c = t >> 3, ch = t & 7;
    int4 v = *reinterpret_cast<const int4*>(zp + ((size_t)(b * C_ + c)) * HW_ + hw0 + ch * 8);
    *reinterpret_cast<int4*>(&zt[c][ch * 8]) = v;
  }
  __syncthreads();
  float s = 0.f, q = 0.f;
#pragma unroll 4
  for (int k = 0; k < 32; ++k) {
    float v = bf2f(zt[cq * 32 + k][wq]);
    s += v;
    q += v * v;
  }
  redS[cq][wq] = s;
  redQ[cq][wq] = q;
  __syncthreads();
  if (cq == 0) {
    float ss = redS[0][wq] + redS[1][wq] + redS[2][wq] + redS[3][wq];
    float qq = redQ[0][wq] + redQ[1][wq] + redQ[2][wq] + redQ[3][wq];
    float m = ss * (1.0f / C_);
    float var = qq * (1.0f / C_) - m * m;
    meanArr[wq] = m;
    invArr[wq] = rsqrtf(fmaxf(var, 0.f) + EPS_);
  }
  __syncthreads();
  float m = meanArr[wq], iv = invArr[wq];
#pragma unroll
  for (int g = 0; g < 4; ++g) {
    unsigned short pk[8];
#pragma unroll
    for (int i = 0; i < 8; ++i) {
      int c = cq * 32 + g * 8 + i;
      float v = bf2f(zt[c][wq]);
      pk[i] = f2bf_bits((v - m) * iv * ln2_w[c] + ln2_b[c]);
    }
    int4 t;
    __builtin_memcpy(&t, pk, 16);
    *reinterpret_cast<int4*>(&yt[wq][cq * 32 + g * 8]) = t;
  }
  __syncthreads();
  unsigned short* yp = reinterpret_cast<unsigned short*>(yT);
#pragma unroll
  for (int i = 0; i < 4; ++i) {
    int t = tid + 256 * i;
    int row = t >> 4, ch = t & 15;
    int4 v = *reinterpret_cast<const int4*>(&yt[row][ch * 8]);
    *reinterpret_cast<int4*>(yp + ((size_t)(b * HW_ + hw0 + row)) * C_ + ch * 8) = v;
  }
}

// ---------------- K4: expand MFMA GEMM + GELU + gx2 + eT ----------------
// REVERT to (256,4): r9's (256,5) capped VGPR at 48 < acc's 64 -> scratch spill
// (WRITE 113->213 MB). 4 blocks/CU measured 50 µs twice (r5,r6). Keep the
// conflict-free Es chunk-swizzle (bank-conflict 401K -> 0 in r9).
__global__ __launch_bounds__(256, 4) void expand_mfma(const bf16* __restrict__ yT,
                                                      const bf16* __restrict__ weB,
                                                      bf16* __restrict__ eT,
                                                      float* __restrict__ gx2) {
  int j0 = blockIdx.x * 128;    // 784 tiles (fast dim keeps yT L3-hot)
  int o0 = blockIdx.y * 128;    // 4 tiles
  int tid = threadIdx.x;
  int lane = tid & 63, wid = tid >> 6;
  int wm = wid >> 1, wn = wid & 1;
  int quad = lane >> 4, l15 = lane & 15;
  __shared__ __align__(16) char smem[32768];   // dbuf: buf t @ (t&1)*16384 {A 8K, B 8K}; Es union
  const short* yS = reinterpret_cast<const short*>(yT);
  const short* weS = reinterpret_cast<const short*>(weB);
  int sr = (wid * 2) * 16 + (lane >> 2);
  int scp = lane & 3;
  auto STAGE = [&](int bs, int k0) {
#pragma unroll
    for (int i = 0; i < 2; ++i) {
      int seg = wid * 2 + i;
      int r = sr + i * 16;
      int c = scp ^ ((r >> 1) & 3);
      char* base = smem + bs * 16384 + seg * 1024;
      glds16(yS + (size_t)(j0 + r) * C_ + k0 + c * 8, base);
      glds16(weS + (size_t)(o0 + r) * C_ + k0 + c * 8, base + 8192);
    }
  };
  f32x4 acc[4][4] = {};
  STAGE(0, 0);
  __syncthreads();
#pragma unroll
  for (int t = 0; t < 4; ++t) {
    if (t < 3) STAGE((t + 1) & 1, (t + 1) * 32);
    const char* ba = smem + (t & 1) * 16384;
    int sx = (quad ^ ((l15 >> 1) & 3)) * 16;
    short8 a[4], bfr[4];
#pragma unroll
    for (int mf = 0; mf < 4; ++mf)
      a[mf] = *reinterpret_cast<const short8*>(ba + (wm * 64 + mf * 16 + l15) * 64 + sx);
#pragma unroll
    for (int nf = 0; nf < 4; ++nf)
      bfr[nf] = *reinterpret_cast<const short8*>(ba + 8192 + (wn * 64 + nf * 16 + l15) * 64 + sx);
#pragma unroll
    for (int mf = 0; mf < 4; ++mf)
#pragma unroll
      for (int nf = 0; nf < 4; ++nf)
        acc[mf][nf] = __builtin_amdgcn_mfma_f32_16x16x32_bf16(a[mf], bfr[nf], acc[mf][nf], 0, 0, 0);
    __syncthreads();   // drains vmcnt(0): next-chunk stage complete; this-buf reads done
  }
  // epilogue: GELU + gx2 from regs, Es chunk-swizzled [128 rows][128 o] (32 KB, bufs dead)
  unsigned short* Ep = reinterpret_cast<unsigned short*>(smem);
#pragma unroll
  for (int mf = 0; mf < 4; ++mf) {
    int jm = j0 + wm * 64 + mf * 16;       // 16-aligned -> single b per m-frag
    int bb = jm / HW_;
    int jrow = wm * 64 + mf * 16 + quad * 4;
#pragma unroll
    for (int nf = 0; nf < 4; ++nf) {
      int oc = wn * 64 + nf * 16 + l15;
      int lchunk = oc >> 3, lrem = oc & 7;
      float g2 = 0.f;
#pragma unroll
      for (int r = 0; r < 4; ++r) {
        float ge = fast_gelu(acc[mf][nf][r]);
        g2 += ge * ge;
        int row = jrow + r;
        Ep[row * 128 + ((lchunk ^ (row & 15)) << 3) + lrem] = f2bf_bits(ge);
      }
      g2 += __shfl_xor(g2, 16, 64);
      g2 += __shfl_xor(g2, 32, 64);
      if (quad == 0) atomicAdd(&gx2[bb * CE_ + o0 + oc], g2);
    }
  }
  __syncthreads();
  unsigned short* eP = reinterpret_cast<unsigned short*>(eT);
#pragma unroll
  for (int i = 0; i < 8; ++i) {   // 128 rows x 16 chunks(16B): 4 full rows / wave-instr
    int t = tid + 256 * i;
    int row = t >> 4, ch = t & 15;
    int4 v = *reinterpret_cast<const int4*>(Ep + row * 128 + ((ch ^ (row & 15)) << 3));
    *reinterpret_cast<int4*>(eP + (size_t)(j0 + row) * CE_ + o0 + ch * 8) = v;
  }
}

// ---------------- K5: GRN scale + ws scaling, merged (per-block redundant reduction) ----------------
__global__ __launch_bounds__(256) void grn_scale_ws(const float* __restrict__ gx2,
                                                    const float* __restrict__ gamma,
                                                    const float* __restrict__ ws,
                                                    bf16* __restrict__ sws) {
  int c = blockIdx.x;
  int b = blockIdx.y;
  int tid = threadIdx.x;
  __shared__ float gxs[CE_];
  __shared__ float red[4];
  __shared__ float invm;
  const float* gp = gx2 + b * CE_;
  float g0 = sqrtf(gp[tid]);
  float g1 = sqrtf(gp[tid + 256]);
  gxs[tid] = g0;
  gxs[tid + 256] = g1;
  float s = wave_reduce_sum(g0 + g1);
  int lane = tid & 63, wid = tid >> 6;
  if (lane == 0) red[wid] = s;
  __syncthreads();
  if (tid == 0) invm = 1.0f / ((red[0] + red[1] + red[2] + red[3]) * (1.0f / CE_) + EPS_);
  __syncthreads();
  float im = invm;
  const float* wp = ws + (size_t)c * CE_;
  bf16* op = sws + ((size_t)(b * C_ + c)) * CE_;
#pragma unroll
  for (int i = tid; i < CE_; i += 256) {
    float sc = 1.0f + gamma[i] * (gxs[i] * im);
    op[i] = __float2bfloat16(wp[i] * sc);
  }
}

// ---------------- K6: shrink MFMA GEMM + bias + residual ----------------
// 64-hw tiles, grid (49,B) EXACT. k=64 glds dbuf (A 8K + B 16K per buf, 48 KB total)
// -> 3 blocks/CU. Swizzle c^=r&7 on source and read. Single-phase epilogue.
__global__ __launch_bounds__(256, 3) void shrink_mfma(const bf16* __restrict__ eT,
                                                      const bf16* __restrict__ sws,
                                                      const float* __restrict__ sb,
                                                      const float* __restrict__ x,
                                                      float* __restrict__ out) {
  int hw0 = blockIdx.x * 64;    // 49*64 = 3136 exact
  int b = blockIdx.y;
  int tid = threadIdx.x;
  int lane = tid & 63, wid = tid >> 6;
  int wm = wid >> 1, wn = wid & 1;
  int quad = lane >> 4, l15 = lane & 15;
  __shared__ __align__(16) char smem[49152];   // dbuf @ (t&1)*24576 {A 8K, B 16K}; Ef union
  const short* eS  = reinterpret_cast<const short*>(eT) + (size_t)b * HW_ * CE_;
  const short* wsS = reinterpret_cast<const short*>(sws) + (size_t)b * C_ * CE_;
  int lr = lane >> 3;                           // row-within-segment
  int lc = lane & 7;                            // chunk position in 128B row
  auto STAGE = [&](int bs, int k0) {
    char* base = smem + bs * 24576;
#pragma unroll
    for (int i = 0; i < 2; ++i) {               // A: 8 segs of 8 rows (64 rows)
      int seg = wid * 2 + i;
      int r = seg * 8 + lr;
      int c = lc ^ (r & 7);
      glds16(eS + (size_t)(hw0 + r) * CE_ + k0 + c * 8, base + seg * 1024);
    }
#pragma unroll
    for (int i = 0; i < 4; ++i) {               // B: 16 segs of 8 rows (128 rows)
      int seg = wid * 4 + i;
      int r = seg * 8 + lr;
      int c = lc ^ (r & 7);
      glds16(wsS + (size_t)r * CE_ + k0 + c * 8, base + 8192 + seg * 1024);
    }
  };
  f32x4 acc[2][4] = {};
  STAGE(0, 0);
  __syncthreads();
#pragma unroll 1
  for (int t = 0; t < 8; ++t) {
    if (t < 7) STAGE((t + 1) & 1, (t + 1) * 64);
    const char* ba = smem + (t & 1) * 24576;
#pragma unroll
    for (int ks = 0; ks < 2; ++ks) {
      short8 a[2], bfr[4];
#pragma unroll
      for (int mf = 0; mf < 2; ++mf) {
        int row = wm * 32 + mf * 16 + l15;
        int cp = (ks * 4 + quad) ^ (row & 7);
        a[mf] = *reinterpret_cast<const short8*>(ba + row * 128 + cp * 16);
      }
#pragma unroll
      for (int nf = 0; nf < 4; ++nf) {
        int row = wn * 64 + nf * 16 + l15;
        int cp = (ks * 4 + quad) ^ (row & 7);
        bfr[nf] = *reinterpret_cast<const short8*>(ba + 8192 + row * 128 + cp * 16);
      }
#pragma unroll
      for (int mf = 0; mf < 2; ++mf)
#pragma unroll
        for (int nf = 0; nf < 4; ++nf)
          acc[mf][nf] = __builtin_amdgcn_mfma_f32_16x16x32_bf16(a[mf], bfr[nf], acc[mf][nf], 0, 0, 0);
    }
    __syncthreads();
  }
  // single-phase f32 transpose epilogue: Ef[128 c][68] (34.8 KB, bufs dead), + sb + residual
  float (*Ef)[68] = reinterpret_cast<float(*)[68]>(&smem[0]);
#pragma unroll
  for (int mf = 0; mf < 2; ++mf) {
    int hwr = wm * 32 + mf * 16 + quad * 4;
#pragma unroll
    for (int nf = 0; nf < 4; ++nf)
      *reinterpret_cast<f32x4*>(&Ef[wn * 64 + nf * 16 + l15][hwr]) = acc[mf][nf];
  }
  __syncthreads();
  // store: 128 c-rows x 64 hw (256B/row), 16 chunks(16B)/row -> 4 full rows / wave-instr
#pragma unroll
  for (int i = 0; i < 8; ++i) {
    int t = tid + 256 * i;
    int row = t >> 4, ch = t & 15;
    int hw = hw0 + ch * 4;
    size_t base = ((size_t)(b * C_ + row)) * HW_ + hw;
    float add = sb[row];
    f32x4 av = *reinterpret_cast<const f32x4*>(&Ef[row][ch * 4]);
    float4 xv = *reinterpret_cast<const float4*>(x + base);
    float4 ov;
    ov.x = av.x + add + xv.x;
    ov.y = av.y + add + xv.y;
    ov.z = av.z + add + xv.z;
    ov.w = av.w + add + xv.w;
    *reinterpret_cast<float4*>(out + base) = ov;
  }
}

extern "C" void kernel_launch(void* const* d_in, const int* in_sizes, int n_in,
                              void* d_out, int out_size, void* d_ws, size_t ws_size,
                              hipStream_t stream) {
  (void)in_sizes; (void)n_in; (void)out_size; (void)ws_size;
  const float* x        = (const float*)d_in[0];
  const float* w_fc1    = (const float*)d_in[1];
  const float* ln1_w    = (const float*)d_in[2];
  const float* ln1_b    = (const float*)d_in[3];
  const float* w_fc2    = (const float*)d_in[4];
  const float* ln2_w    = (const float*)d_in[5];
  const float* ln2_b    = (const float*)d_in[6];
  const float* w_expand = (const float*)d_in[7];
  const float* w_shrink = (const float*)d_in[8];
  const float* gamma    = (const float*)d_in[9];
  const float* beta     = (const float*)d_in[10];
  float* out = (float*)d_out;

  char* ws = (char*)d_ws;
  float* pooled = (float*)(ws + 0);
  float* dyn    = (float*)(ws + 16384);
  float* gx2    = (float*)(ws + 425984);
  float* sb     = (float*)(ws + 557056);
  bf16*  weB    = (bf16*)(ws + 557568);
  bf16*  wsB    = (bf16*)(ws + 688640);
  bf16*  yT     = (bf16*)(ws + 819712);
  bf16*  sws    = (bf16*)(ws + 819712);   // alias: yT dead after expand_mfma
  bf16*  eT     = (bf16*)(ws + 26509824);
  bf16*  z      = eT;                     // alias: z dead before expand_mfma writes eT

  prep_all<<<4800, 256, 0, stream>>>(w_expand, w_shrink, beta, x, weB, wsB, gx2, sb, pooled);
  fc_kernel<<<B_, 256, 0, stream>>>(pooled, w_fc1, ln1_w, ln1_b, w_fc2, dyn);
  conv_kernel<<<B_ * C_, 256, 0, stream>>>(x, dyn, z);
  ln_kernel<<<dim3(49, B_), 256, 0, stream>>>(z, ln2_w, ln2_b, yT);
  expand_mfma<<<dim3(784, 4), 256, 0, stream>>>(yT, weB, eT, gx2);
  grn_scale_ws<<<dim3(C_, B_), 256, 0, stream>>>(gx2, gamma, w_shrink, sws);
  shrink_mfma<<<dim3(49, B_), 256, 0, stream>>>(eT, sws, sb, x, out);
}

// Round 11
// 263.351 us; speedup vs baseline: 1.1577x; 1.0057x over previous
//
#include <hip/hip_runtime.h>
#include <hip/hip_bf16.h>

#define B_   32
#define C_   128
#define H_   56
#define W_   56
#define HW_  (H_*W_)
#define BHW_ (B_*HW_)        // 100352 = 784*128; 3136 = 49*64
#define K5_  5
#define KK_  25
#define CR_  32
#define CE_  512
#define EPS_ 1e-6f

typedef __hip_bfloat16 bf16;
typedef __attribute__((ext_vector_type(8))) short short8;   // 8 bf16 (4 VGPRs)
typedef __attribute__((ext_vector_type(4))) float f32x4;

// ---------- workspace layout (bytes) ----------
// pooled fp32 [B*C]        @ 0         (16,384)
// dyn    fp32 [B*C*25]     @ 16,384    (409,600)
// gx2    fp32 [B*CE]       @ 425,984   (65,536)
// sb     fp32 [C]          @ 557,056   (512)
// weB    bf16 [CE*C]       @ 557,568   (131,072)
// wsB    bf16 [C*CE]       @ 688,640   (131,072)
// yT     bf16 [BHW][C]     @ 819,712   (25,690,112)
//   sws bf16 [B][C][CE] (4,194,304 B) ALIASES head of yT (yT dead after expand)
// eT     bf16 [BHW][CE]    @ 26,509,824 (102,760,448)  (z aliases head of eT)

__device__ __forceinline__ float wave_reduce_sum(float v) {
#pragma unroll
  for (int off = 32; off > 0; off >>= 1) v += __shfl_down(v, off, 64);
  return v;
}
__device__ __forceinline__ float bf2f(unsigned short u) {
  return __uint_as_float(((unsigned)u) << 16);
}
__device__ __forceinline__ unsigned short f2bf_bits(float f) {
  bf16 h = __float2bfloat16(f);
  unsigned short u;
  __builtin_memcpy(&u, &h, 2);
  return u;
}
// sigmoid-form GELU: v * sigmoid(1.702 v)
__device__ __forceinline__ float fast_gelu(float v) {
  float t = __expf(-1.702f * v);
  return v * __builtin_amdgcn_rcpf(1.0f + t);
}
// async global->LDS, 16B per lane; LDS dest = wave-uniform base + lane*16
__device__ __forceinline__ void glds16(const void* g, void* l) {
  __builtin_amdgcn_global_load_lds(
      (const __attribute__((address_space(1))) unsigned int*)g,
      (__attribute__((address_space(3))) unsigned int*)l, 16, 0, 0);
}

// ---------------- K0: merged prep (weights->bf16, gx2=0, sb, pool) ----------------
// blocks 0..575: convert/zero; 576..703: sb[c]; 704..4799: pool (bc = bx-704)
__global__ __launch_bounds__(256) void prep_all(const float* __restrict__ we,
                                                const float* __restrict__ ws,
                                                const float* __restrict__ beta,
                                                const float* __restrict__ x,
                                                bf16* __restrict__ weB,
                                                bf16* __restrict__ wsB,
                                                float* __restrict__ gx2,
                                                float* __restrict__ sb,
                                                float* __restrict__ pooled) {
  int bx = blockIdx.x;
  if (bx < 576) {
    int i = bx * 256 + threadIdx.x;
    if (i < CE_ * C_)          weB[i] = __float2bfloat16(we[i]);
    else if (i < 2 * CE_ * C_) wsB[i - CE_ * C_] = __float2bfloat16(ws[i - CE_ * C_]);
    else                       gx2[i - 2 * CE_ * C_] = 0.f;
  } else if (bx < 704) {
    int c = bx - 576;
    const float* wp = ws + (size_t)c * CE_;
    float acc = 0.f;
    for (int o = threadIdx.x; o < CE_; o += 256) acc += wp[o] * beta[o];
    acc = wave_reduce_sum(acc);
    __shared__ float red[4];
    int lane = threadIdx.x & 63, wid = threadIdx.x >> 6;
    if (lane == 0) red[wid] = acc;
    __syncthreads();
    if (threadIdx.x == 0) sb[c] = red[0] + red[1] + red[2] + red[3];
  } else {
    int bc = bx - 704;
    const float4* xp4 = reinterpret_cast<const float4*>(x + (size_t)bc * HW_);
    float s = 0.f;
    for (int i = threadIdx.x; i < 784; i += 256) {
      float4 v = xp4[i];
      s += (v.x + v.y) + (v.z + v.w);
    }
    s = wave_reduce_sum(s);
    __shared__ float redp[4];
    int lane = threadIdx.x & 63, wid = threadIdx.x >> 6;
    if (lane == 0) redp[wid] = s;
    __syncthreads();
    if (threadIdx.x == 0) pooled[bc] = (redp[0] + redp[1] + redp[2] + redp[3]) * (1.0f / HW_);
  }
}

// ---------------- K2: fc1 -> LN1 -> fc2 (dyn weights) ----------------
__global__ __launch_bounds__(256) void fc_kernel(const float* __restrict__ pooled,
                                                 const float* __restrict__ w_fc1,
                                                 const float* __restrict__ ln1_w,
                                                 const float* __restrict__ ln1_b,
                                                 const float* __restrict__ w_fc2,
                                                 float* __restrict__ dyn) {
  int b = blockIdx.x;
  int tid = threadIdx.x;
  __shared__ float sp[C_];
  __shared__ float sh[CR_];
  __shared__ float shn[CR_];
  __shared__ float stats[2];
  if (tid < C_) sp[tid] = pooled[b * C_ + tid];
  __syncthreads();
  if (tid < CR_) {
    float acc = 0.f;
    const float* wr = w_fc1 + tid * C_;
#pragma unroll 4
    for (int c = 0; c < C_; ++c) acc += sp[c] * wr[c];
    sh[tid] = acc;
  }
  __syncthreads();
  if (tid == 0) {
    float u = 0.f;
    for (int j = 0; j < CR_; ++j) u += sh[j];
    u *= (1.0f / CR_);
    float v = 0.f;
    for (int j = 0; j < CR_; ++j) { float d = sh[j] - u; v += d * d; }
    v *= (1.0f / CR_);
    stats[0] = u;
    stats[1] = rsqrtf(v + EPS_);
  }
  __syncthreads();
  if (tid < CR_) shn[tid] = (sh[tid] - stats[0]) * stats[1] * ln1_w[tid] + ln1_b[tid];
  __syncthreads();
  for (int i = tid; i < C_ * KK_; i += 256) {
    const float* wr = w_fc2 + i * CR_;
    float acc = 0.f;
#pragma unroll
    for (int j = 0; j < CR_; ++j) acc += shn[j] * wr[j];
    dyn[b * (C_ * KK_) + i] = acc;
  }
}

// ---------------- K3a: dynamic depthwise 5x5 conv -> z (bf16, [b][c][hw]) ----------------
__global__ __launch_bounds__(256) void conv_kernel(const float* __restrict__ x,
                                                   const float* __restrict__ dyn,
                                                   bf16* __restrict__ z) {
  int bc = blockIdx.x;
  int b = bc >> 7;
  int c = bc & 127;
  int tid = threadIdx.x;
  __shared__ float xs[(H_ + 4) * 64];   // rows -2..57 at (r+2)*64; 15,360 B
  __shared__ float wks[KK_];
  {  // zero halo rows 0,1,58,59 (full) — 4*64 = 256 = blockDim
    int r = tid >> 6;
    int rr = (r < 2) ? r : (56 + r);
    xs[rr * 64 + (tid & 63)] = 0.f;
  }
  if (tid < 224) {  // zero halo cols 0,1,58,59 of data rows 2..57
    int r = tid >> 2, q = tid & 3;
    int col = (q < 2) ? q : (56 + q);
    xs[(r + 2) * 64 + col] = 0.f;
  }
  if (tid < KK_) wks[tid] = dyn[b * (C_ * KK_) + c * KK_ + tid];
  const float4* xp4 = reinterpret_cast<const float4*>(x + (size_t)bc * HW_);
  for (int i = tid; i < 784; i += 256) {
    float4 v = xp4[i];
    int h = i / 14, w4 = (i % 14) * 4;
    float* dst = &xs[(h + 2) * 64 + 2 + w4];
    dst[0] = v.x; dst[1] = v.y; dst[2] = v.z; dst[3] = v.w;
  }
  __syncthreads();
  float wr[KK_];
#pragma unroll
  for (int j = 0; j < KK_; ++j) wr[j] = wks[j];
  for (int g = tid; g < 784; g += 256) {
    int h = g / 14;
    int w4 = (g % 14) * 4;
    float a0 = 0.f, a1 = 0.f, a2 = 0.f, a3 = 0.f;
#pragma unroll
    for (int dh = 0; dh < K5_; ++dh) {
      const float* row = &xs[(h + dh) * 64 + w4];   // padded row h+dh-2
      float4 va = *reinterpret_cast<const float4*>(row);
      float4 vb = *reinterpret_cast<const float4*>(row + 4);
      float v0 = va.x, v1 = va.y, v2 = va.z, v3 = va.w;
      float v4 = vb.x, v5 = vb.y, v6 = vb.z, v7 = vb.w;
      float u0 = wr[dh * 5 + 0], u1 = wr[dh * 5 + 1], u2 = wr[dh * 5 + 2];
      float u3 = wr[dh * 5 + 3], u4 = wr[dh * 5 + 4];
      a0 += v0 * u0 + v1 * u1 + v2 * u2 + v3 * u3 + v4 * u4;
      a1 += v1 * u0 + v2 * u1 + v3 * u2 + v4 * u3 + v5 * u4;
      a2 += v2 * u0 + v3 * u1 + v4 * u2 + v5 * u3 + v6 * u4;
      a3 += v3 * u0 + v4 * u1 + v5 * u2 + v6 * u3 + v7 * u4;
    }
    size_t base = (size_t)bc * HW_ + h * W_ + w4;
    ushort4 pk = make_ushort4(f2bf_bits(a0), f2bf_bits(a1), f2bf_bits(a2), f2bf_bits(a3));
    *reinterpret_cast<ushort4*>(reinterpret_cast<unsigned short*>(z) + base) = pk;
  }
}

// ---------------- K3b: channel LN over z -> yT (bf16, [j][c]); vectorized loads ----------------
__global__ __launch_bounds__(256) void ln_kernel(const bf16* __restrict__ z,
                                                 const float* __restrict__ ln2_w,
                                                 const float* __restrict__ ln2_b,
                                                 bf16* __restrict__ yT) {
  int hw0 = blockIdx.x * 64;
  int b = blockIdx.y;
  int tid = threadIdx.x;
  int wq = tid & 63;
  int cq = tid >> 6;
  __shared__ unsigned short zt[C_][64];     // 16 KB
  __shared__ unsigned short yt[64][136];    // 17.4 KB transpose buffer (rows 16B-aligned)
  __shared__ float redS[4][64];
  __shared__ float redQ[4][64];
  __shared__ float meanArr[64];
  __shared__ float invArr[64];
  const unsigned short* zp = reinterpret_cast<const unsigned short*>(z);
#pragma unroll
  for (int i = 0; i < 4; ++i) {
    int t = tid + 256 * i;
    int c = t >> 3, ch = t & 7;
    int4 v = *reinterpret_cast<const int4*>(zp + ((size_t)(b * C_ + c)) * HW_ + hw0 + ch * 8);
    *reinterpret_cast<int4*>(&zt[c][ch * 8]) = v;
  }
  __syncthreads();
  float s = 0.f, q = 0.f;
#pragma unroll 4
  for (int k = 0; k < 32; ++k) {
    float v = bf2f(zt[cq * 32 + k][wq]);
    s += v;
    q += v * v;
  }
  redS[cq][wq] = s;
  redQ[cq][wq] = q;
  __syncthreads();
  if (cq == 0) {
    float ss = redS[0][wq] + redS[1][wq] + redS[2][wq] + redS[3][wq];
    float qq = redQ[0][wq] + redQ[1][wq] + redQ[2][wq] + redQ[3][wq];
    float m = ss * (1.0f / C_);
    float var = qq * (1.0f / C_) - m * m;
    meanArr[wq] = m;
    invArr[wq] = rsqrtf(fmaxf(var, 0.f) + EPS_);
  }
  __syncthreads();
  float m = meanArr[wq], iv = invArr[wq];
#pragma unroll
  for (int g = 0; g < 4; ++g) {
    unsigned short pk[8];
#pragma unroll
    for (int i = 0; i < 8; ++i) {
      int c = cq * 32 + g * 8 + i;
      float v = bf2f(zt[c][wq]);
      pk[i] = f2bf_bits((v - m) * iv * ln2_w[c] + ln2_b[c]);
    }
    int4 t;
    __builtin_memcpy(&t, pk, 16);
    *reinterpret_cast<int4*>(&yt[wq][cq * 32 + g * 8]) = t;
  }
  __syncthreads();
  unsigned short* yp = reinterpret_cast<unsigned short*>(yT);
#pragma unroll
  for (int i = 0; i < 4; ++i) {
    int t = tid + 256 * i;
    int row = t >> 4, ch = t & 15;
    int4 v = *reinterpret_cast<const int4*>(&yt[row][ch * 8]);
    *reinterpret_cast<int4*>(yp + ((size_t)(b * HW_ + hw0 + row)) * C_ + ch * 8) = v;
  }
}

// ---------------- K4: expand MFMA GEMM + GELU + gx2 + eT ----------------
// r6-exact configuration (measured 50.2 µs twice): glds16 dbuf staging (4 blocks/CU),
// padded Es[128][136] epilogue. r10's chunk-swizzled Es traded a free 2-way bank
// conflict (401K, below the free threshold) for +9% VALUBusy -> +5 µs. Reverted.
__global__ __launch_bounds__(256, 4) void expand_mfma(const bf16* __restrict__ yT,
                                                      const bf16* __restrict__ weB,
                                                      bf16* __restrict__ eT,
                                                      float* __restrict__ gx2) {
  int j0 = blockIdx.x * 128;    // 784 tiles (fast dim keeps yT L3-hot)
  int o0 = blockIdx.y * 128;    // 4 tiles
  int tid = threadIdx.x;
  int lane = tid & 63, wid = tid >> 6;
  int wm = wid >> 1, wn = wid & 1;
  int quad = lane >> 4, l15 = lane & 15;
  __shared__ __align__(16) char smem[34816];   // dbuf: buf t @ (t&1)*16384 {A 8K, B 8K}; Es union
  const short* yS = reinterpret_cast<const short*>(yT);
  const short* weS = reinterpret_cast<const short*>(weB);
  int sr = (wid * 2) * 16 + (lane >> 2);
  int scp = lane & 3;
  auto STAGE = [&](int bs, int k0) {
#pragma unroll
    for (int i = 0; i < 2; ++i) {
      int seg = wid * 2 + i;
      int r = sr + i * 16;
      int c = scp ^ ((r >> 1) & 3);
      char* base = smem + bs * 16384 + seg * 1024;
      glds16(yS + (size_t)(j0 + r) * C_ + k0 + c * 8, base);
      glds16(weS + (size_t)(o0 + r) * C_ + k0 + c * 8, base + 8192);
    }
  };
  f32x4 acc[4][4] = {};
  STAGE(0, 0);
  __syncthreads();
#pragma unroll
  for (int t = 0; t < 4; ++t) {
    if (t < 3) STAGE((t + 1) & 1, (t + 1) * 32);
    const char* ba = smem + (t & 1) * 16384;
    int sx = (quad ^ ((l15 >> 1) & 3)) * 16;
    short8 a[4], bfr[4];
#pragma unroll
    for (int mf = 0; mf < 4; ++mf)
      a[mf] = *reinterpret_cast<const short8*>(ba + (wm * 64 + mf * 16 + l15) * 64 + sx);
#pragma unroll
    for (int nf = 0; nf < 4; ++nf)
      bfr[nf] = *reinterpret_cast<const short8*>(ba + 8192 + (wn * 64 + nf * 16 + l15) * 64 + sx);
#pragma unroll
    for (int mf = 0; mf < 4; ++mf)
#pragma unroll
      for (int nf = 0; nf < 4; ++nf)
        acc[mf][nf] = __builtin_amdgcn_mfma_f32_16x16x32_bf16(a[mf], bfr[nf], acc[mf][nf], 0, 0, 0);
    __syncthreads();   // drains vmcnt(0): next-chunk stage complete; this-buf reads done
  }
  // epilogue: GELU + gx2 from regs, then padded bf16 tile -> coalesced 256B-row stores
  short (*Es)[136] = reinterpret_cast<short(*)[136]>(&smem[0]);   // bufs dead
#pragma unroll
  for (int mf = 0; mf < 4; ++mf) {
    int jm = j0 + wm * 64 + mf * 16;       // 16-aligned -> single b per m-frag
    int bb = jm / HW_;
    int jrow = wm * 64 + mf * 16 + quad * 4;
#pragma unroll
    for (int nf = 0; nf < 4; ++nf) {
      int oc = wn * 64 + nf * 16 + l15;
      float g2 = 0.f;
#pragma unroll
      for (int r = 0; r < 4; ++r) {
        float ge = fast_gelu(acc[mf][nf][r]);
        g2 += ge * ge;
        Es[jrow + r][oc] = (short)f2bf_bits(ge);
      }
      g2 += __shfl_xor(g2, 16, 64);
      g2 += __shfl_xor(g2, 32, 64);
      if (quad == 0) atomicAdd(&gx2[bb * CE_ + o0 + oc], g2);
    }
  }
  __syncthreads();
  unsigned short* eP = reinterpret_cast<unsigned short*>(eT);
#pragma unroll
  for (int i = 0; i < 8; ++i) {   // 128 rows x 16 chunks(16B): 4 full rows / wave-instr
    int t = tid + 256 * i;
    int row = t >> 4, ch = t & 15;
    int4 v = *reinterpret_cast<const int4*>(&Es[row][ch * 8]);
    *reinterpret_cast<int4*>(eP + (size_t)(j0 + row) * CE_ + o0 + ch * 8) = v;
  }
}

// ---------------- K5: GRN scale + ws scaling, merged (per-block redundant reduction) ----------------
__global__ __launch_bounds__(256) void grn_scale_ws(const float* __restrict__ gx2,
                                                    const float* __restrict__ gamma,
                                                    const float* __restrict__ ws,
                                                    bf16* __restrict__ sws) {
  int c = blockIdx.x;
  int b = blockIdx.y;
  int tid = threadIdx.x;
  __shared__ float gxs[CE_];
  __shared__ float red[4];
  __shared__ float invm;
  const float* gp = gx2 + b * CE_;
  float g0 = sqrtf(gp[tid]);
  float g1 = sqrtf(gp[tid + 256]);
  gxs[tid] = g0;
  gxs[tid + 256] = g1;
  float s = wave_reduce_sum(g0 + g1);
  int lane = tid & 63, wid = tid >> 6;
  if (lane == 0) red[wid] = s;
  __syncthreads();
  if (tid == 0) invm = 1.0f / ((red[0] + red[1] + red[2] + red[3]) * (1.0f / CE_) + EPS_);
  __syncthreads();
  float im = invm;
  const float* wp = ws + (size_t)c * CE_;
  bf16* op = sws + ((size_t)(b * C_ + c)) * CE_;
#pragma unroll
  for (int i = tid; i < CE_; i += 256) {
    float sc = 1.0f + gamma[i] * (gxs[i] * im);
    op[i] = __float2bfloat16(wp[i] * sc);
  }
}

// ---------------- K6: shrink MFMA GEMM + bias + residual ----------------
// 64-hw tiles, grid (49,B) EXACT. k=64 glds dbuf (A 8K + B 16K per buf, 48 KB total)
// -> 3 blocks/CU. Swizzle c^=r&7 on source and read. Single-phase epilogue.
__global__ __launch_bounds__(256, 3) void shrink_mfma(const bf16* __restrict__ eT,
                                                      const bf16* __restrict__ sws,
                                                      const float* __restrict__ sb,
                                                      const float* __restrict__ x,
                                                      float* __restrict__ out) {
  int hw0 = blockIdx.x * 64;    // 49*64 = 3136 exact
  int b = blockIdx.y;
  int tid = threadIdx.x;
  int lane = tid & 63, wid = tid >> 6;
  int wm = wid >> 1, wn = wid & 1;
  int quad = lane >> 4, l15 = lane & 15;
  __shared__ __align__(16) char smem[49152];   // dbuf @ (t&1)*24576 {A 8K, B 16K}; Ef union
  const short* eS  = reinterpret_cast<const short*>(eT) + (size_t)b * HW_ * CE_;
  const short* wsS = reinterpret_cast<const short*>(sws) + (size_t)b * C_ * CE_;
  int lr = lane >> 3;                           // row-within-segment
  int lc = lane & 7;                            // chunk position in 128B row
  auto STAGE = [&](int bs, int k0) {
    char* base = smem + bs * 24576;
#pragma unroll
    for (int i = 0; i < 2; ++i) {               // A: 8 segs of 8 rows (64 rows)
      int seg = wid * 2 + i;
      int r = seg * 8 + lr;
      int c = lc ^ (r & 7);
      glds16(eS + (size_t)(hw0 + r) * CE_ + k0 + c * 8, base + seg * 1024);
    }
#pragma unroll
    for (int i = 0; i < 4; ++i) {               // B: 16 segs of 8 rows (128 rows)
      int seg = wid * 4 + i;
      int r = seg * 8 + lr;
      int c = lc ^ (r & 7);
      glds16(wsS + (size_t)r * CE_ + k0 + c * 8, base + 8192 + seg * 1024);
    }
  };
  f32x4 acc[2][4] = {};
  STAGE(0, 0);
  __syncthreads();
#pragma unroll 1
  for (int t = 0; t < 8; ++t) {
    if (t < 7) STAGE((t + 1) & 1, (t + 1) * 64);
    const char* ba = smem + (t & 1) * 24576;
#pragma unroll
    for (int ks = 0; ks < 2; ++ks) {
      short8 a[2], bfr[4];
#pragma unroll
      for (int mf = 0; mf < 2; ++mf) {
        int row = wm * 32 + mf * 16 + l15;
        int cp = (ks * 4 + quad) ^ (row & 7);
        a[mf] = *reinterpret_cast<const short8*>(ba + row * 128 + cp * 16);
      }
#pragma unroll
      for (int nf = 0; nf < 4; ++nf) {
        int row = wn * 64 + nf * 16 + l15;
        int cp = (ks * 4 + quad) ^ (row & 7);
        bfr[nf] = *reinterpret_cast<const short8*>(ba + 8192 + row * 128 + cp * 16);
      }
#pragma unroll
      for (int mf = 0; mf < 2; ++mf)
#pragma unroll
        for (int nf = 0; nf < 4; ++nf)
          acc[mf][nf] = __builtin_amdgcn_mfma_f32_16x16x32_bf16(a[mf], bfr[nf], acc[mf][nf], 0, 0, 0);
    }
    __syncthreads();
  }
  // single-phase f32 transpose epilogue: Ef[128 c][68] (34.8 KB, bufs dead), + sb + residual
  float (*Ef)[68] = reinterpret_cast<float(*)[68]>(&smem[0]);
#pragma unroll
  for (int mf = 0; mf < 2; ++mf) {
    int hwr = wm * 32 + mf * 16 + quad * 4;
#pragma unroll
    for (int nf = 0; nf < 4; ++nf)
      *reinterpret_cast<f32x4*>(&Ef[wn * 64 + nf * 16 + l15][hwr]) = acc[mf][nf];
  }
  __syncthreads();
  // store: 128 c-rows x 64 hw (256B/row), 16 chunks(16B)/row -> 4 full rows / wave-instr
#pragma unroll
  for (int i = 0; i < 8; ++i) {
    int t = tid + 256 * i;
    int row = t >> 4, ch = t & 15;
    int hw = hw0 + ch * 4;
    size_t base = ((size_t)(b * C_ + row)) * HW_ + hw;
    float add = sb[row];
    f32x4 av = *reinterpret_cast<const f32x4*>(&Ef[row][ch * 4]);
    float4 xv = *reinterpret_cast<const float4*>(x + base);
    float4 ov;
    ov.x = av.x + add + xv.x;
    ov.y = av.y + add + xv.y;
    ov.z = av.z + add + xv.z;
    ov.w = av.w + add + xv.w;
    *reinterpret_cast<float4*>(out + base) = ov;
  }
}

extern "C" void kernel_launch(void* const* d_in, const int* in_sizes, int n_in,
                              void* d_out, int out_size, void* d_ws, size_t ws_size,
                              hipStream_t stream) {
  (void)in_sizes; (void)n_in; (void)out_size; (void)ws_size;
  const float* x        = (const float*)d_in[0];
  const float* w_fc1    = (const float*)d_in[1];
  const float* ln1_w    = (const float*)d_in[2];
  const float* ln1_b    = (const float*)d_in[3];
  const float* w_fc2    = (const float*)d_in[4];
  const float* ln2_w    = (const float*)d_in[5];
  const float* ln2_b    = (const float*)d_in[6];
  const float* w_expand = (const float*)d_in[7];
  const float* w_shrink = (const float*)d_in[8];
  const float* gamma    = (const float*)d_in[9];
  const float* beta     = (const float*)d_in[10];
  float* out = (float*)d_out;

  char* ws = (char*)d_ws;
  float* pooled = (float*)(ws + 0);
  float* dyn    = (float*)(ws + 16384);
  float* gx2    = (float*)(ws + 425984);
  float* sb     = (float*)(ws + 557056);
  bf16*  weB    = (bf16*)(ws + 557568);
  bf16*  wsB    = (bf16*)(ws + 688640);
  bf16*  yT     = (bf16*)(ws + 819712);
  bf16*  sws    = (bf16*)(ws + 819712);   // alias: yT dead after expand_mfma
  bf16*  eT     = (bf16*)(ws + 26509824);
  bf16*  z      = eT;                     // alias: z dead before expand_mfma writes eT

  prep_all<<<4800, 256, 0, stream>>>(w_expand, w_shrink, beta, x, weB, wsB, gx2, sb, pooled);
  fc_kernel<<<B_, 256, 0, stream>>>(pooled, w_fc1, ln1_w, ln1_b, w_fc2, dyn);
  conv_kernel<<<B_ * C_, 256, 0, stream>>>(x, dyn, z);
  ln_kernel<<<dim3(49, B_), 256, 0, stream>>>(z, ln2_w, ln2_b, yT);
  expand_mfma<<<dim3(784, 4), 256, 0, stream>>>(yT, weB, eT, gx2);
  grn_scale_ws<<<dim3(C_, B_), 256, 0, stream>>>(gx2, gamma, w_shrink, sws);
  shrink_mfma<<<dim3(49, B_), 256, 0, stream>>>(eT, sws, sb, x, out);
}